// Round 8
// baseline (506.440 us; speedup 1.0000x reference)
//
#include <hip/hip_runtime.h>
#include <math.h>

// ---------------------------------------------------------------------------
// BayesianAttention (B=8, L=512, D=1024, H=16, DK=DV=64, k_weibull=0.5)
// Numerics plan:
//   - Q/K projections + QK^T: split-bf16 (hi/lo) 3-MFMA => ~fp32-ish precision
//   - V projection, prior MLP, PV, output GEMM: plain bf16 MFMA
//   - attention restructure: pass A spills scaled logits s (f32, 128MB arena),
//     pass B is K-free: spill-read + gumbel/lgamma + softmax-2 + PV. LDS of
//     the two passes overlays (19.7KB) -> 6 blocks/CU target.
//   - EPS-floor lp = log(exp(s-C)+1e-20) kept exact: ~0.7% of rows have
//     u_min < 1.3e-5 where G ~ -50..-100 and the floored element dominates.
//   - S2 = sum exp(log(softmax+1e-20)) = B*H*L exactly -> constant in k_kl.
//   - KL: kl_mean = (-S1 + L*T2 + S2) / (B*H*L*L)
// ---------------------------------------------------------------------------

typedef __bf16 bh_t;
typedef bh_t  bh8  __attribute__((ext_vector_type(8)));
typedef float f32x4 __attribute__((ext_vector_type(4)));

#define MFMA_BF16 __builtin_amdgcn_mfma_f32_16x16x32_bf16

// ---- scratch layout in a device-global arena (no dependence on ws_size) ----
static constexpr size_t P2 = 4096ull*1024ull*2ull;   // bf16 [4096][1024] plane
static constexpr size_t W2 = 1024ull*1024ull*2ull;   // bf16 [1024][1024] plane
static constexpr size_t O_QHI = 0;
static constexpr size_t O_QLO = O_QHI + P2;
static constexpr size_t O_KHI = O_QLO + P2;
static constexpr size_t O_KLO = O_KHI + P2;
static constexpr size_t O_VB  = O_KLO + P2;
static constexpr size_t O_VT  = O_VB  + P2;          // bf16 [128][64][512] V^T
static constexpr size_t O_WQH = O_VT  + P2;
static constexpr size_t O_WQL = O_WQH + W2;
static constexpr size_t O_WKH = O_WQL + W2;
static constexpr size_t O_WKL = O_WKH + W2;
static constexpr size_t O_WVH = O_WKL + W2;
static constexpr size_t O_WVL = O_WVH + W2;
static constexpr size_t O_WOH = O_WVL + W2;
static constexpr size_t O_WOL = O_WOH + W2;
static constexpr size_t O_WP1H = O_WOL + W2;
static constexpr size_t O_WP1L = O_WP1H + 1024ull*64ull*2ull;
static constexpr size_t O_DG   = O_WP1L + 1024ull*64ull*2ull;
static constexpr size_t O_ALPHA= O_DG + 65536ull*4ull;
static constexpr size_t O_HO   = O_ALPHA + 65536ull*4ull;               // bf16 [4096][1024]
static constexpr size_t O_SS   = O_HO + P2;                             // f32 logit spill, 128 MB
static constexpr size_t O_ACC  = O_SS + 1024ull*32768ull*4ull;          // 3 doubles
static constexpr size_t WS_TOTAL = O_ACC + 256;

__device__ __align__(256) unsigned char g_ws[WS_TOTAL];

// ---------------------------------------------------------------------------
// slim lgamma: reflection + shift-to-(>=4) + 2-term Stirling, all hw trans.
// abs err ~1e-5 away from poles; poles only where weight -> 0 / ref is inf too.
__device__ __forceinline__ float lgamma_fast(float x)
{
    float ax = (x < 0.5f) ? (1.0f - x) : x;          // ax >= 0.5
    float p  = ax*(ax+1.f)*(ax+2.f)*(ax+3.f);
    bool  sm = ax < 4.0f;
    float lsh = sm ? __logf(p) : 0.0f;
    float y   = sm ? (ax + 4.0f) : ax;               // y >= 4
    float ly  = __logf(y);
    float inv = __builtin_amdgcn_rcpf(y);
    float i2  = inv * inv;
    float stir = fmaf(y - 0.5f, ly, -y) + 0.91893853320467274f
               + inv * fmaf(-2.7777777777e-3f, i2, 8.3333333333e-2f);
    float core = stir - lsh;                         // lgamma(ax)
    // reflection: lgamma(x) = ln(pi) - ln|sin(pi x)| - lgamma(1-x)
    float r  = x - rintf(x);                         // |r| <= 0.5
    float sp = __sinf(3.14159265358979f * r);
    float rres = 1.14472988584940017f - __logf(fabsf(sp)) - core;
    return (x < 0.5f) ? rres : core;
}

// ---------------------------------------------------------------------------
__global__ void k_zero(double* a)
{
    if (threadIdx.x < 4) a[threadIdx.x] = 0.0;
}

// transpose f32 [rows][cols] -> bf16 hi/lo [cols][rows]
__global__ __launch_bounds__(256) void k_transpose_split(
    const float* __restrict__ in, bh_t* __restrict__ oh, bh_t* __restrict__ ol,
    int rows, int cols)
{
    __shared__ float tile[64][65];
    const int bc = blockIdx.x * 64, br = blockIdx.y * 64;
    const int t = threadIdx.x;
    const int r = t >> 2, c0 = (t & 3) * 16;
#pragma unroll
    for (int i = 0; i < 16; i += 4) {
        float4 v = *(const float4*)(in + (size_t)(br + r) * cols + bc + c0 + i);
        tile[r][c0+i]   = v.x; tile[r][c0+i+1] = v.y;
        tile[r][c0+i+2] = v.z; tile[r][c0+i+3] = v.w;
    }
    __syncthreads();
    bh8 hv[2], lv[2];
#pragma unroll
    for (int i = 0; i < 16; i++) {
        float x = tile[c0 + i][r];
        bh_t hh = (bh_t)x;
        hv[i >> 3][i & 7] = hh;
        lv[i >> 3][i & 7] = (bh_t)(x - (float)hh);
    }
    size_t ob = (size_t)(bc + r) * rows + br + c0;
    *(bh8*)(oh + ob)     = hv[0];
    *(bh8*)(oh + ob + 8) = hv[1];
    *(bh8*)(ol + ob)     = lv[0];
    *(bh8*)(ol + ob + 8) = lv[1];
}

// V^T: VB [b*512+l][h*64+dv] -> VT [(b*16+h)*64+dv][l]
__global__ __launch_bounds__(256) void k_transV(
    const bh_t* __restrict__ VB, bh_t* __restrict__ VT)
{
    __shared__ bh_t tile[64][72];
    const int lt = blockIdx.x, h = blockIdx.y, b = blockIdx.z;
    const int t = threadIdx.x;
    const int r = t >> 2, c0 = (t & 3) * 16;
    const bh_t* src = VB + ((size_t)(b*512 + lt*64 + r)) * 1024 + h*64 + c0;
    *(bh8*)&tile[r][c0]     = *(const bh8*)src;
    *(bh8*)&tile[r][c0 + 8] = *(const bh8*)(src + 8);
    __syncthreads();
    bh8 o0, o1;
#pragma unroll
    for (int j = 0; j < 8; j++) o0[j] = tile[c0 + j][r];
#pragma unroll
    for (int j = 0; j < 8; j++) o1[j] = tile[c0 + 8 + j][r];
    size_t dst = ((size_t)((b*16 + h)*64) + r) * 512 + lt*64 + c0;
    *(bh8*)(VT + dst)     = o0;
    *(bh8*)(VT + dst + 8) = o1;
}

// C[4096][1024] = A[4096][1024] @ W[1024][1024] + bias
// A: f32 (ABF=0, converted inline) or pre-converted bf16 plane (ABF=1).
// W pre-transposed bf16 hi/lo planes [n][k].
// OMODE 0: write bf16 hi+lo planes; 1: write bf16 plane; 2: write f32.
template<bool SPLIT, int OMODE, bool ABF>
__global__ __launch_bounds__(256) void k_gemm(
    const float* __restrict__ A, const bh_t* __restrict__ ABH,
    const bh_t* __restrict__ WH, const bh_t* __restrict__ WL,
    const float* __restrict__ bias,
    bh_t* __restrict__ oh, bh_t* __restrict__ ol, float* __restrict__ of)
{
    __shared__ __align__(16) bh_t Ah[64][40];
    __shared__ __align__(16) bh_t Al[64][40];
    __shared__ __align__(16) bh_t Bh[64][40];
    __shared__ __align__(16) bh_t Bl[64][40];
    const int n0 = blockIdx.x * 64, m0 = blockIdx.y * 64;
    const int t = threadIdx.x;
    const int lane = t & 63, w = t >> 6;
    const int lr = lane & 15, kg = lane >> 4;
    const int wm = (w & 1) * 32, wn = (w >> 1) * 32;
    const int ar = t >> 2, ac = (t & 3) * 8;
    f32x4 acc[2][2] = {};

    for (int kt = 0; kt < 1024; kt += 32) {
        __syncthreads();
        {
            if constexpr (ABF) {
                *(bh8*)&Ah[ar][ac] = *(const bh8*)(ABH + (size_t)(m0 + ar) * 1024 + kt + ac);
            } else {
                const float* ap = A + (size_t)(m0 + ar) * 1024 + kt + ac;
                float4 v0 = *(const float4*)ap;
                float4 v1 = *(const float4*)(ap + 4);
                float xs[8] = {v0.x, v0.y, v0.z, v0.w, v1.x, v1.y, v1.z, v1.w};
                bh8 h, l;
#pragma unroll
                for (int i = 0; i < 8; i++) {
                    bh_t hh = (bh_t)xs[i];
                    h[i] = hh;
                    l[i] = (bh_t)(xs[i] - (float)hh);
                }
                *(bh8*)&Ah[ar][ac] = h;
                if constexpr (SPLIT) *(bh8*)&Al[ar][ac] = l;
            }
            size_t wb = (size_t)(n0 + ar) * 1024 + kt + ac;
            *(bh8*)&Bh[ar][ac] = *(const bh8*)(WH + wb);
            if constexpr (SPLIT) *(bh8*)&Bl[ar][ac] = *(const bh8*)(WL + wb);
        }
        __syncthreads();
#pragma unroll
        for (int fm = 0; fm < 2; fm++) {
            bh8 a_h = *(bh8*)&Ah[wm + fm*16 + lr][kg * 8];
#pragma unroll
            for (int fn = 0; fn < 2; fn++) {
                bh8 b_h = *(bh8*)&Bh[wn + fn*16 + lr][kg * 8];
                acc[fm][fn] = MFMA_BF16(a_h, b_h, acc[fm][fn], 0, 0, 0);
                if constexpr (SPLIT) {
                    bh8 a_l = *(bh8*)&Al[wm + fm*16 + lr][kg * 8];
                    bh8 b_l = *(bh8*)&Bl[wn + fn*16 + lr][kg * 8];
                    acc[fm][fn] = MFMA_BF16(a_h, b_l, acc[fm][fn], 0, 0, 0);
                    acc[fm][fn] = MFMA_BF16(a_l, b_h, acc[fm][fn], 0, 0, 0);
                }
            }
        }
    }
#pragma unroll
    for (int fm = 0; fm < 2; fm++)
#pragma unroll
    for (int fn = 0; fn < 2; fn++) {
        int col = n0 + wn + fn*16 + lr;
        float bv = bias[col];
#pragma unroll
        for (int r = 0; r < 4; r++) {
            int row = m0 + wm + fm*16 + kg*4 + r;
            float c = acc[fm][fn][r] + bv;
            size_t idx = (size_t)row * 1024 + col;
            if constexpr (OMODE == 0) {
                bh_t hh = (bh_t)c;
                oh[idx] = hh;
                ol[idx] = (bh_t)(c - (float)hh);
            } else if constexpr (OMODE == 1) {
                oh[idx] = (bh_t)c;
            } else {
                of[idx] = c;
            }
        }
    }
}

// dot_gamma[b,h,l] = Wp2 . leakyrelu(K_head[b,h,l,:] @ Wp1 + bp1) + bp2
__global__ __launch_bounds__(256) void k_prior(
    const bh_t* __restrict__ KH, const bh_t* __restrict__ WP1T,
    const float* __restrict__ bp1, const float* __restrict__ wp2,
    const float* __restrict__ bp2, float* __restrict__ DG)
{
    __shared__ __align__(16) bh_t Kt[64][72];
    __shared__ __align__(16) bh_t Wt[64][72];
    const int lt = blockIdx.x, h = blockIdx.y, b = blockIdx.z;
    const int t = threadIdx.x, lane = t & 63, w = t >> 6;
    const int lr = lane & 15, kg = lane >> 4;
    {
        int r = t >> 2, j0 = (t & 3) * 16;
        const bh_t* src = KH + ((size_t)(b*512 + lt*64 + r)) * 1024 + h*64 + j0;
        *(bh8*)&Kt[r][j0]     = *(const bh8*)src;
        *(bh8*)&Kt[r][j0 + 8] = *(const bh8*)(src + 8);
    }
    __syncthreads();
    bh8 af0 = *(bh8*)&Kt[w*16 + lr][kg * 8];
    bh8 af1 = *(bh8*)&Kt[w*16 + lr][32 + kg * 8];
    float dgp[4] = {0.f, 0.f, 0.f, 0.f};
    for (int dt = 0; dt < 16; dt++) {
        __syncthreads();
        {
            int r = t >> 2, j0 = (t & 3) * 16;
            const bh_t* src = WP1T + (size_t)(dt*64 + r) * 64 + j0;
            *(bh8*)&Wt[r][j0]     = *(const bh8*)src;
            *(bh8*)&Wt[r][j0 + 8] = *(const bh8*)(src + 8);
        }
        __syncthreads();
#pragma unroll
        for (int fn = 0; fn < 4; fn++) {
            bh8 b0 = *(bh8*)&Wt[fn*16 + lr][kg * 8];
            bh8 b1 = *(bh8*)&Wt[fn*16 + lr][32 + kg * 8];
            f32x4 acc = {};
            acc = MFMA_BF16(af0, b0, acc, 0, 0, 0);
            acc = MFMA_BF16(af1, b1, acc, 0, 0, 0);
            int d = dt*64 + fn*16 + lr;
            float bpv = bp1[d], wvv = wp2[d];
#pragma unroll
            for (int r = 0; r < 4; r++) {
                float hv = acc[r] + bpv;
                hv = (hv >= 0.f) ? hv : 0.01f * hv;
                dgp[r] = fmaf(hv, wvv, dgp[r]);
            }
        }
    }
#pragma unroll
    for (int r = 0; r < 4; r++) {
        float v = dgp[r];
        v += __shfl_xor(v, 1); v += __shfl_xor(v, 2);
        v += __shfl_xor(v, 4); v += __shfl_xor(v, 8);
        dgp[r] = v;
    }
    if (lr == 0) {
        float b2 = bp2[0];
        int bh = b * 16 + h;
#pragma unroll
        for (int r = 0; r < 4; r++)
            DG[(size_t)bh*512 + lt*64 + w*16 + kg*4 + r] = dgp[r] + b2;
    }
}

// alpha = softmax_k(dot_gamma); accumulate alpha-only KL terms into acc[2]
__global__ __launch_bounds__(512) void k_alpha(
    const float* __restrict__ DG, float* __restrict__ AL, double* __restrict__ acc)
{
    __shared__ float red[512];
    const int bh = blockIdx.x, t = threadIdx.x;
    float v = DG[(size_t)bh * 512 + t];
    red[t] = v; __syncthreads();
    for (int s = 256; s > 0; s >>= 1) { if (t < s) red[t] = fmaxf(red[t], red[t+s]); __syncthreads(); }
    float m = red[0]; __syncthreads();
    float e = expf(v - m);
    red[t] = e; __syncthreads();
    for (int s = 256; s > 0; s >>= 1) { if (t < s) red[t] += red[t+s]; __syncthreads(); }
    float ssum = red[0]; __syncthreads();
    float a = e / ssum;                 // * BETA_GAMMA (=1)
    AL[(size_t)bh * 512 + t] = a;
    // lg1 + 2*eulergamma = 0.6931471805599453 + 1.1544313298030658
    float t2 = a * 1.8475785103630112f + lgammaf(a + 1e-20f);
    red[t] = t2; __syncthreads();
    for (int s = 256; s > 0; s >>= 1) { if (t < s) red[t] += red[t+s]; __syncthreads(); }
    if (t == 0) atomicAdd(&acc[2], (double)red[0]);
}

// fused stochastic attention: one block per (b,h, 64-row q-chunk)
// pass A: QK split-MFMA -> spill scaled logits s (f32); online (M1, Z1)
// pass B: K-free. spill-read + gumbel/lgamma chain + softmax-2 + PV
// LDS overlays: passA {KtH,KtL} / passB {Vt, Sl}  -> ~19.7 KB
__global__ __launch_bounds__(256, 6) void k_attn(
    const bh_t* __restrict__ QH, const bh_t* __restrict__ QL,
    const bh_t* __restrict__ KH, const bh_t* __restrict__ KL,
    const bh_t* __restrict__ VT, const float* __restrict__ U,
    const float* __restrict__ AL, bh_t* __restrict__ HOB,
    float* __restrict__ SS, double* __restrict__ acc)
{
    __shared__ __align__(16) unsigned char lraw[2][64*72*2];
    __shared__ float Asm[64];
    __shared__ float red[256];

    const int flat = blockIdx.x;
    const int bh = flat & 127, qc = flat >> 7;   // 8 q-chunks of one bh share an XCD
    const int b = bh >> 4, h = bh & 15;
    const int t = threadIdx.x, w = t >> 6, lane = t & 63;
    const int lr = lane & 15, kg = lane >> 4;
    const int q0 = qc * 64 + w * 16;
    const int sr = t >> 2, sj = (t & 3) * 16;
    float* SSp = SS + (size_t)flat * 32768 + (size_t)w * 8192;

    float C[4];   // per-q-row M1 + lnZ1, carried from pass A to pass B

    // ---- pass A: logits (split-bf16 MFMA), spill s, online M1/Z1 ----
    {
        bh_t (*KtH)[72] = (bh_t(*)[72])lraw[0];
        bh_t (*KtL)[72] = (bh_t(*)[72])lraw[1];
        bh8 qh[2], ql[2];
        {
            size_t qb = ((size_t)(b * 512) + q0 + lr) * 1024 + h * 64;
            qh[0] = *(const bh8*)(QH + qb + kg * 8);
            qh[1] = *(const bh8*)(QH + qb + 32 + kg * 8);
            ql[0] = *(const bh8*)(QL + qb + kg * 8);
            ql[1] = *(const bh8*)(QL + qb + 32 + kg * 8);
        }
        float M1[4], Z1[4];
#pragma unroll
        for (int r = 0; r < 4; r++) { M1[r] = -INFINITY; Z1[r] = 0.f; }

        for (int kt = 0; kt < 8; kt++) {
            __syncthreads();
            {
                size_t src = ((size_t)(b*512 + kt*64 + sr)) * 1024 + h*64 + sj;
                *(bh8*)&KtH[sr][sj]     = *(const bh8*)(KH + src);
                *(bh8*)&KtH[sr][sj + 8] = *(const bh8*)(KH + src + 8);
                *(bh8*)&KtL[sr][sj]     = *(const bh8*)(KL + src);
                *(bh8*)&KtL[sr][sj + 8] = *(const bh8*)(KL + src + 8);
            }
            __syncthreads();
            f32x4 av[4];
#pragma unroll
            for (int fn = 0; fn < 4; fn++) {
                f32x4 a = {};
#pragma unroll
                for (int ks = 0; ks < 2; ks++) {
                    bh8 kb  = *(bh8*)&KtH[fn*16 + lr][ks*32 + kg*8];
                    bh8 kl2 = *(bh8*)&KtL[fn*16 + lr][ks*32 + kg*8];
                    a = MFMA_BF16(qh[ks], kb,  a, 0, 0, 0);
                    a = MFMA_BF16(qh[ks], kl2, a, 0, 0, 0);
                    a = MFMA_BF16(ql[ks], kb,  a, 0, 0, 0);
                }
#pragma unroll
                for (int r = 0; r < 4; r++) a[r] *= 8.0f;   // att / SCALE, SCALE=1/8
                av[fn] = a;
                *(f32x4*)(SSp + ((size_t)(kt*4 + fn) * 64 + lane) * 4) = a;
            }
#pragma unroll
            for (int r = 0; r < 4; r++) {
                float mx = fmaxf(fmaxf(av[0][r], av[1][r]), fmaxf(av[2][r], av[3][r]));
                mx = fmaxf(mx, __shfl_xor(mx, 1));
                mx = fmaxf(mx, __shfl_xor(mx, 2));
                mx = fmaxf(mx, __shfl_xor(mx, 4));
                mx = fmaxf(mx, __shfl_xor(mx, 8));
                float nm = fmaxf(M1[r], mx);
                float es = __expf(av[0][r]-nm) + __expf(av[1][r]-nm)
                         + __expf(av[2][r]-nm) + __expf(av[3][r]-nm);
                es += __shfl_xor(es, 1); es += __shfl_xor(es, 2);
                es += __shfl_xor(es, 4); es += __shfl_xor(es, 8);
                Z1[r] = Z1[r] * __expf(M1[r] - nm) + es;
                M1[r] = nm;
            }
        }
#pragma unroll
        for (int r = 0; r < 4; r++) C[r] = M1[r] + logf(Z1[r]);
    }

    // ---- pass B: spill-read; lp + gumbel/lgamma; softmax-2 + PV ----
    bh_t (*Vt)[72] = (bh_t(*)[72])lraw[0];
    bh_t (*Sl)[16][72] = (bh_t(*)[16][72])lraw[1];
    float M2[4], Z2[4];
    f32x4 oacc[4] = {};
#pragma unroll
    for (int r = 0; r < 4; r++) { M2[r] = -INFINITY; Z2[r] = 0.f; }
    float S1f = 0.f;
    const float* Up = U + ((size_t)bh * 512 + q0 + kg * 4) * 512;

    for (int kt = 0; kt < 8; kt++) {
        __syncthreads();
        {   // stage V^T (vectorized) + alpha tile
            const bh_t* vsrc = VT + ((size_t)bh * 64 + sr) * 512 + kt*64 + sj;
            *(bh8*)&Vt[sr][sj]     = *(const bh8*)vsrc;
            *(bh8*)&Vt[sr][sj + 8] = *(const bh8*)(vsrc + 8);
            if (t < 64) Asm[t] = AL[(size_t)bh * 512 + kt * 64 + t];
        }
        __syncthreads();
        f32x4 wv[4];
#pragma unroll
        for (int fn = 0; fn < 4; fn++) {
            f32x4 s4 = *(const f32x4*)(SSp + ((size_t)(kt*4 + fn) * 64 + lane) * 4);
            float alv = Asm[fn * 16 + lr];
            int k = kt * 64 + fn * 16 + lr;
#pragma unroll
            for (int r = 0; r < 4; r++) {
                float s  = s4[r] - C[r];                  // logit - (M1+lnZ1)
                float ex = __expf(s);                     // = softmax-1 prob
                float lp = __logf(ex + 1e-20f);           // exact EPS-floor
                float u  = Up[(size_t)r * 512 + k];
                float tt = (1.0f - u) + 1e-20f;
                float gl = 1e-20f - __logf(tt);           // -log(1-u)+eps
                float g  = __logf(gl);
                float G  = lgamma_fast(fmaf(2.0f, g, 3.0f)); // 1+1/k+(1/k)*gumbel
                wv[fn][r] = lp - G;
                S1f = fmaf(alv, lp, S1f);
            }
        }
#pragma unroll
        for (int r = 0; r < 4; r++) {
            float mx = fmaxf(fmaxf(wv[0][r], wv[1][r]), fmaxf(wv[2][r], wv[3][r]));
            mx = fmaxf(mx, __shfl_xor(mx, 1));
            mx = fmaxf(mx, __shfl_xor(mx, 2));
            mx = fmaxf(mx, __shfl_xor(mx, 4));
            mx = fmaxf(mx, __shfl_xor(mx, 8));
            float nm = fmaxf(M2[r], mx);
            float sc = __expf(M2[r] - nm);               // exp(-inf)=0, exp(0)=1
            float zs = 0.f;
#pragma unroll
            for (int fn = 0; fn < 4; fn++) {
                float sv = __expf(wv[fn][r] - nm);
                zs += sv;
                Sl[w][kg * 4 + r][fn * 16 + lr] = (bh_t)sv;
            }
            zs += __shfl_xor(zs, 1); zs += __shfl_xor(zs, 2);
            zs += __shfl_xor(zs, 4); zs += __shfl_xor(zs, 8);
            Z2[r] = fmaf(Z2[r], sc, zs);
            M2[r] = nm;
#pragma unroll
            for (int fo = 0; fo < 4; fo++) oacc[fo][r] *= sc;
        }
        // no block barrier: Sl is per-wave (LDS ops are wave-program-ordered);
        // Vt was barriered at stage and only rewritten after next barrier.
        bh8 sa0 = *(bh8*)&Sl[w][lr][kg*8];
        bh8 sa1 = *(bh8*)&Sl[w][lr][32 + kg*8];
#pragma unroll
        for (int fo = 0; fo < 4; fo++) {
            bh8 v0 = *(bh8*)&Vt[fo*16 + lr][kg*8];
            bh8 v1 = *(bh8*)&Vt[fo*16 + lr][32 + kg*8];
            oacc[fo] = MFMA_BF16(sa0, v0, oacc[fo], 0, 0, 0);
            oacc[fo] = MFMA_BF16(sa1, v1, oacc[fo], 0, 0, 0);
        }
    }
    float rz[4];
#pragma unroll
    for (int r = 0; r < 4; r++) rz[r] = 1.0f / Z2[r];
    // head output (bf16): HO[b, q, h*64+dv]
#pragma unroll
    for (int fo = 0; fo < 4; fo++) {
#pragma unroll
        for (int r = 0; r < 4; r++) {
            int q = q0 + kg * 4 + r;
            int dv = fo * 16 + lr;
            HOB[((size_t)(b * 512 + q)) * 1024 + h * 64 + dv] = (bh_t)(oacc[fo][r] * rz[r]);
        }
    }
    red[t] = S1f; __syncthreads();
    for (int s = 128; s > 0; s >>= 1) { if (t < s) red[t] += red[t+s]; __syncthreads(); }
    if (t == 0) atomicAdd(&acc[0], (double)red[0]);
}

__global__ void k_kl(const double* __restrict__ acc, float* __restrict__ out)
{
    if (threadIdx.x == 0 && blockIdx.x == 0) {
        // S2 = sum(exp(log(softmax+1e-20))) = B*H*L (+ BHL*L*1e-20, negligible)
        double kl = (-acc[0] + 512.0 * acc[2] + 65536.0) / 33554432.0;
        out[4194304] = (float)kl;
    }
}

// ---------------------------------------------------------------------------
extern "C" void kernel_launch(void* const* d_in, const int* in_sizes, int n_in,
                              void* d_out, int out_size, void* d_ws, size_t ws_size,
                              hipStream_t stream)
{
    (void)in_sizes; (void)n_in; (void)d_ws; (void)ws_size; (void)out_size;
    const float* queries = (const float*)d_in[0];
    const float* keys    = (const float*)d_in[1];
    const float* values  = (const float*)d_in[2];
    const float* unif    = (const float*)d_in[3];
    const float* Wq = (const float*)d_in[4];  const float* bq = (const float*)d_in[5];
    const float* Wk = (const float*)d_in[6];  const float* bk = (const float*)d_in[7];
    const float* Wv = (const float*)d_in[8];  const float* bv = (const float*)d_in[9];
    const float* Wo = (const float*)d_in[10]; const float* bo = (const float*)d_in[11];
    const float* Wp1 = (const float*)d_in[12]; const float* bp1 = (const float*)d_in[13];
    const float* Wp2 = (const float*)d_in[14]; const float* bp2 = (const float*)d_in[15];

    unsigned char* ws = nullptr;
    hipGetSymbolAddress((void**)&ws, HIP_SYMBOL(g_ws));

    bh_t* QHI = (bh_t*)(ws + O_QHI); bh_t* QLO = (bh_t*)(ws + O_QLO);
    bh_t* KHI = (bh_t*)(ws + O_KHI); bh_t* KLO = (bh_t*)(ws + O_KLO);
    bh_t* VBp = (bh_t*)(ws + O_VB);  bh_t* VTp = (bh_t*)(ws + O_VT);
    bh_t* WQH = (bh_t*)(ws + O_WQH); bh_t* WQL = (bh_t*)(ws + O_WQL);
    bh_t* WKH = (bh_t*)(ws + O_WKH); bh_t* WKL = (bh_t*)(ws + O_WKL);
    bh_t* WVH = (bh_t*)(ws + O_WVH); bh_t* WVL = (bh_t*)(ws + O_WVL);
    bh_t* WOH = (bh_t*)(ws + O_WOH); bh_t* WOL = (bh_t*)(ws + O_WOL);
    bh_t* WP1H = (bh_t*)(ws + O_WP1H); bh_t* WP1L = (bh_t*)(ws + O_WP1L);
    float* DG    = (float*)(ws + O_DG);
    float* ALPHA = (float*)(ws + O_ALPHA);
    bh_t*  HOB   = (bh_t*)(ws + O_HO);
    float* SS    = (float*)(ws + O_SS);
    double* ACC  = (double*)(ws + O_ACC);
    float* outF  = (float*)d_out;

    k_zero<<<1, 64, 0, stream>>>(ACC);

    k_transpose_split<<<dim3(16,16), 256, 0, stream>>>(Wq,  WQH,  WQL, 1024, 1024);
    k_transpose_split<<<dim3(16,16), 256, 0, stream>>>(Wk,  WKH,  WKL, 1024, 1024);
    k_transpose_split<<<dim3(16,16), 256, 0, stream>>>(Wv,  WVH,  WVL, 1024, 1024);
    k_transpose_split<<<dim3(16,16), 256, 0, stream>>>(Wo,  WOH,  WOL, 1024, 1024);
    k_transpose_split<<<dim3(16,1),  256, 0, stream>>>(Wp1, WP1H, WP1L, 64, 1024);

    k_gemm<true, 0,false><<<dim3(16,64), 256, 0, stream>>>(queries, nullptr, WQH, WQL, bq, QHI, QLO, nullptr);
    k_gemm<true, 0,false><<<dim3(16,64), 256, 0, stream>>>(keys,    nullptr, WKH, WKL, bk, KHI, KLO, nullptr);
    k_gemm<false,1,false><<<dim3(16,64), 256, 0, stream>>>(values,  nullptr, WVH, WVL, bv, VBp, nullptr, nullptr);

    k_transV<<<dim3(8,16,8), 256, 0, stream>>>(VBp, VTp);
    k_prior<<<dim3(8,16,8), 256, 0, stream>>>(KHI, WP1H, bp1, Wp2, bp2, DG);
    k_alpha<<<128, 512, 0, stream>>>(DG, ALPHA, ACC);

    k_attn<<<1024, 256, 0, stream>>>(QHI, QLO, KHI, KLO, VTp, unif, ALPHA, HOB, SS, ACC);

    k_gemm<false,2,true><<<dim3(16,64), 256, 0, stream>>>(nullptr, HOB, WOH, WOL, bo, nullptr, nullptr, outF);
    k_kl<<<1, 1, 0, stream>>>(ACC, outF);
}

// Round 9
// 468.048 us; speedup vs baseline: 1.0820x; 1.0820x over previous
//
#include <hip/hip_runtime.h>
#include <math.h>

// ---------------------------------------------------------------------------
// BayesianAttention (B=8, L=512, D=1024, H=16, DK=DV=64, k_weibull=0.5)
// Numerics plan:
//   - Q/K projections + QK^T: split-bf16 (hi/lo) 3-MFMA => ~fp32-ish precision
//   - V projection, prior MLP, PV, output GEMM: plain bf16 MFMA
//   - k_attn (R7 structure, R9 occupancy fixes):
//       pass A: QK MFMA + online (M1,Z1) + Gumbel/lgamma G chain interleaved
//               with the MFMAs (fills their latency), G spilled as FP16
//               (64 MB arena; live set ~98 MB @6 blocks/CU stays L3-resident)
//       pass B: K-restage + 3-MFMA logit recompute + short chain (exp+log)
//               + softmax-2 + PV. V read direct from global (L2-resident/XCD).
//               Sl overlaid into KtL wave-slices behind a 3rd barrier.
//       LDS 38.4 -> 19.7 KB; __launch_bounds__(256,6) -> 24 waves/CU target.
//   - fp16 G: abs err 2^-11*|G| ~ 0.005 typical << bf16 weight quantization;
//     |G|~300 tail is winner-take-all (normalized output insensitive).
//   - EPS-floor lp = log(exp(s-C)+1e-20) kept exact (load-bearing for ~0.7%
//     of rows where the floored min element dominates softmax-2).
//   - S2 = sum exp(log(softmax+1e-20)) = B*H*L exactly -> constant in k_kl.
//   - KL: kl_mean = (-S1 + L*T2 + S2) / (B*H*L*L)
// ---------------------------------------------------------------------------

typedef __bf16 bh_t;
typedef bh_t  bh8  __attribute__((ext_vector_type(8)));
typedef float f32x4 __attribute__((ext_vector_type(4)));
typedef _Float16 hf_t;
typedef hf_t  hf4  __attribute__((ext_vector_type(4)));

#define MFMA_BF16 __builtin_amdgcn_mfma_f32_16x16x32_bf16

// ---- scratch layout in a device-global arena (no dependence on ws_size) ----
static constexpr size_t P2 = 4096ull*1024ull*2ull;   // bf16 [4096][1024] plane
static constexpr size_t W2 = 1024ull*1024ull*2ull;   // bf16 [1024][1024] plane
static constexpr size_t O_QHI = 0;
static constexpr size_t O_QLO = O_QHI + P2;
static constexpr size_t O_KHI = O_QLO + P2;
static constexpr size_t O_KLO = O_KHI + P2;
static constexpr size_t O_VB  = O_KLO + P2;
static constexpr size_t O_VT  = O_VB  + P2;          // bf16 [128][64][512] V^T
static constexpr size_t O_WQH = O_VT  + P2;
static constexpr size_t O_WQL = O_WQH + W2;
static constexpr size_t O_WKH = O_WQL + W2;
static constexpr size_t O_WKL = O_WKH + W2;
static constexpr size_t O_WVH = O_WKL + W2;
static constexpr size_t O_WVL = O_WVH + W2;
static constexpr size_t O_WOH = O_WVL + W2;
static constexpr size_t O_WOL = O_WOH + W2;
static constexpr size_t O_WP1H = O_WOL + W2;
static constexpr size_t O_WP1L = O_WP1H + 1024ull*64ull*2ull;
static constexpr size_t O_DG   = O_WP1L + 1024ull*64ull*2ull;
static constexpr size_t O_ALPHA= O_DG + 65536ull*4ull;
static constexpr size_t O_HO   = O_ALPHA + 65536ull*4ull;               // bf16 [4096][1024]
static constexpr size_t O_GS   = O_HO + P2;                             // fp16 G spill, 64 MB
static constexpr size_t O_ACC  = O_GS + 1024ull*32768ull*2ull;          // 3 doubles
static constexpr size_t WS_TOTAL = O_ACC + 256;

__device__ __align__(256) unsigned char g_ws[WS_TOTAL];

// ---------------------------------------------------------------------------
// slim lgamma: reflection + shift-to-(>=4) + 2-term Stirling, all hw trans.
// abs err ~1e-5 away from poles; poles only where weight -> 0 / ref is inf too.
__device__ __forceinline__ float lgamma_fast(float x)
{
    float ax = (x < 0.5f) ? (1.0f - x) : x;          // ax >= 0.5
    float p  = ax*(ax+1.f)*(ax+2.f)*(ax+3.f);
    bool  sm = ax < 4.0f;
    float lsh = sm ? __logf(p) : 0.0f;
    float y   = sm ? (ax + 4.0f) : ax;               // y >= 4
    float ly  = __logf(y);
    float inv = __builtin_amdgcn_rcpf(y);
    float i2  = inv * inv;
    float stir = fmaf(y - 0.5f, ly, -y) + 0.91893853320467274f
               + inv * fmaf(-2.7777777777e-3f, i2, 8.3333333333e-2f);
    float core = stir - lsh;                         // lgamma(ax)
    // reflection: lgamma(x) = ln(pi) - ln|sin(pi x)| - lgamma(1-x)
    float r  = x - rintf(x);                         // |r| <= 0.5
    float sp = __sinf(3.14159265358979f * r);
    float rres = 1.14472988584940017f - __logf(fabsf(sp)) - core;
    return (x < 0.5f) ? rres : core;
}

// ---------------------------------------------------------------------------
__global__ void k_zero(double* a)
{
    if (threadIdx.x < 4) a[threadIdx.x] = 0.0;
}

// transpose f32 [rows][cols] -> bf16 hi/lo [cols][rows]
__global__ __launch_bounds__(256) void k_transpose_split(
    const float* __restrict__ in, bh_t* __restrict__ oh, bh_t* __restrict__ ol,
    int rows, int cols)
{
    __shared__ float tile[64][65];
    const int bc = blockIdx.x * 64, br = blockIdx.y * 64;
    const int t = threadIdx.x;
    const int r = t >> 2, c0 = (t & 3) * 16;
#pragma unroll
    for (int i = 0; i < 16; i += 4) {
        float4 v = *(const float4*)(in + (size_t)(br + r) * cols + bc + c0 + i);
        tile[r][c0+i]   = v.x; tile[r][c0+i+1] = v.y;
        tile[r][c0+i+2] = v.z; tile[r][c0+i+3] = v.w;
    }
    __syncthreads();
    bh8 hv[2], lv[2];
#pragma unroll
    for (int i = 0; i < 16; i++) {
        float x = tile[c0 + i][r];
        bh_t hh = (bh_t)x;
        hv[i >> 3][i & 7] = hh;
        lv[i >> 3][i & 7] = (bh_t)(x - (float)hh);
    }
    size_t ob = (size_t)(bc + r) * rows + br + c0;
    *(bh8*)(oh + ob)     = hv[0];
    *(bh8*)(oh + ob + 8) = hv[1];
    *(bh8*)(ol + ob)     = lv[0];
    *(bh8*)(ol + ob + 8) = lv[1];
}

// V^T: VB [b*512+l][h*64+dv] -> VT [(b*16+h)*64+dv][l]
__global__ __launch_bounds__(256) void k_transV(
    const bh_t* __restrict__ VB, bh_t* __restrict__ VT)
{
    __shared__ bh_t tile[64][72];
    const int lt = blockIdx.x, h = blockIdx.y, b = blockIdx.z;
    const int t = threadIdx.x;
    const int r = t >> 2, c0 = (t & 3) * 16;
    const bh_t* src = VB + ((size_t)(b*512 + lt*64 + r)) * 1024 + h*64 + c0;
    *(bh8*)&tile[r][c0]     = *(const bh8*)src;
    *(bh8*)&tile[r][c0 + 8] = *(const bh8*)(src + 8);
    __syncthreads();
    bh8 o0, o1;
#pragma unroll
    for (int j = 0; j < 8; j++) o0[j] = tile[c0 + j][r];
#pragma unroll
    for (int j = 0; j < 8; j++) o1[j] = tile[c0 + 8 + j][r];
    size_t dst = ((size_t)((b*16 + h)*64) + r) * 512 + lt*64 + c0;
    *(bh8*)(VT + dst)     = o0;
    *(bh8*)(VT + dst + 8) = o1;
}

// C[4096][1024] = A[4096][1024] @ W[1024][1024] + bias
// A: f32 (ABF=0, converted inline) or pre-converted bf16 plane (ABF=1).
// W pre-transposed bf16 hi/lo planes [n][k].
// OMODE 0: write bf16 hi+lo planes; 1: write bf16 plane; 2: write f32.
template<bool SPLIT, int OMODE, bool ABF>
__global__ __launch_bounds__(256) void k_gemm(
    const float* __restrict__ A, const bh_t* __restrict__ ABH,
    const bh_t* __restrict__ WH, const bh_t* __restrict__ WL,
    const float* __restrict__ bias,
    bh_t* __restrict__ oh, bh_t* __restrict__ ol, float* __restrict__ of)
{
    __shared__ __align__(16) bh_t Ah[64][40];
    __shared__ __align__(16) bh_t Al[64][40];
    __shared__ __align__(16) bh_t Bh[64][40];
    __shared__ __align__(16) bh_t Bl[64][40];
    const int n0 = blockIdx.x * 64, m0 = blockIdx.y * 64;
    const int t = threadIdx.x;
    const int lane = t & 63, w = t >> 6;
    const int lr = lane & 15, kg = lane >> 4;
    const int wm = (w & 1) * 32, wn = (w >> 1) * 32;
    const int ar = t >> 2, ac = (t & 3) * 8;
    f32x4 acc[2][2] = {};

    for (int kt = 0; kt < 1024; kt += 32) {
        __syncthreads();
        {
            if constexpr (ABF) {
                *(bh8*)&Ah[ar][ac] = *(const bh8*)(ABH + (size_t)(m0 + ar) * 1024 + kt + ac);
            } else {
                const float* ap = A + (size_t)(m0 + ar) * 1024 + kt + ac;
                float4 v0 = *(const float4*)ap;
                float4 v1 = *(const float4*)(ap + 4);
                float xs[8] = {v0.x, v0.y, v0.z, v0.w, v1.x, v1.y, v1.z, v1.w};
                bh8 h, l;
#pragma unroll
                for (int i = 0; i < 8; i++) {
                    bh_t hh = (bh_t)xs[i];
                    h[i] = hh;
                    l[i] = (bh_t)(xs[i] - (float)hh);
                }
                *(bh8*)&Ah[ar][ac] = h;
                if constexpr (SPLIT) *(bh8*)&Al[ar][ac] = l;
            }
            size_t wb = (size_t)(n0 + ar) * 1024 + kt + ac;
            *(bh8*)&Bh[ar][ac] = *(const bh8*)(WH + wb);
            if constexpr (SPLIT) *(bh8*)&Bl[ar][ac] = *(const bh8*)(WL + wb);
        }
        __syncthreads();
#pragma unroll
        for (int fm = 0; fm < 2; fm++) {
            bh8 a_h = *(bh8*)&Ah[wm + fm*16 + lr][kg * 8];
#pragma unroll
            for (int fn = 0; fn < 2; fn++) {
                bh8 b_h = *(bh8*)&Bh[wn + fn*16 + lr][kg * 8];
                acc[fm][fn] = MFMA_BF16(a_h, b_h, acc[fm][fn], 0, 0, 0);
                if constexpr (SPLIT) {
                    bh8 a_l = *(bh8*)&Al[wm + fm*16 + lr][kg * 8];
                    bh8 b_l = *(bh8*)&Bl[wn + fn*16 + lr][kg * 8];
                    acc[fm][fn] = MFMA_BF16(a_h, b_l, acc[fm][fn], 0, 0, 0);
                    acc[fm][fn] = MFMA_BF16(a_l, b_h, acc[fm][fn], 0, 0, 0);
                }
            }
        }
    }
#pragma unroll
    for (int fm = 0; fm < 2; fm++)
#pragma unroll
    for (int fn = 0; fn < 2; fn++) {
        int col = n0 + wn + fn*16 + lr;
        float bv = bias[col];
#pragma unroll
        for (int r = 0; r < 4; r++) {
            int row = m0 + wm + fm*16 + kg*4 + r;
            float c = acc[fm][fn][r] + bv;
            size_t idx = (size_t)row * 1024 + col;
            if constexpr (OMODE == 0) {
                bh_t hh = (bh_t)c;
                oh[idx] = hh;
                ol[idx] = (bh_t)(c - (float)hh);
            } else if constexpr (OMODE == 1) {
                oh[idx] = (bh_t)c;
            } else {
                of[idx] = c;
            }
        }
    }
}

// dot_gamma[b,h,l] = Wp2 . leakyrelu(K_head[b,h,l,:] @ Wp1 + bp1) + bp2
__global__ __launch_bounds__(256) void k_prior(
    const bh_t* __restrict__ KH, const bh_t* __restrict__ WP1T,
    const float* __restrict__ bp1, const float* __restrict__ wp2,
    const float* __restrict__ bp2, float* __restrict__ DG)
{
    __shared__ __align__(16) bh_t Kt[64][72];
    __shared__ __align__(16) bh_t Wt[64][72];
    const int lt = blockIdx.x, h = blockIdx.y, b = blockIdx.z;
    const int t = threadIdx.x, lane = t & 63, w = t >> 6;
    const int lr = lane & 15, kg = lane >> 4;
    {
        int r = t >> 2, j0 = (t & 3) * 16;
        const bh_t* src = KH + ((size_t)(b*512 + lt*64 + r)) * 1024 + h*64 + j0;
        *(bh8*)&Kt[r][j0]     = *(const bh8*)src;
        *(bh8*)&Kt[r][j0 + 8] = *(const bh8*)(src + 8);
    }
    __syncthreads();
    bh8 af0 = *(bh8*)&Kt[w*16 + lr][kg * 8];
    bh8 af1 = *(bh8*)&Kt[w*16 + lr][32 + kg * 8];
    float dgp[4] = {0.f, 0.f, 0.f, 0.f};
    for (int dt = 0; dt < 16; dt++) {
        __syncthreads();
        {
            int r = t >> 2, j0 = (t & 3) * 16;
            const bh_t* src = WP1T + (size_t)(dt*64 + r) * 64 + j0;
            *(bh8*)&Wt[r][j0]     = *(const bh8*)src;
            *(bh8*)&Wt[r][j0 + 8] = *(const bh8*)(src + 8);
        }
        __syncthreads();
#pragma unroll
        for (int fn = 0; fn < 4; fn++) {
            bh8 b0 = *(bh8*)&Wt[fn*16 + lr][kg * 8];
            bh8 b1 = *(bh8*)&Wt[fn*16 + lr][32 + kg * 8];
            f32x4 acc = {};
            acc = MFMA_BF16(af0, b0, acc, 0, 0, 0);
            acc = MFMA_BF16(af1, b1, acc, 0, 0, 0);
            int d = dt*64 + fn*16 + lr;
            float bpv = bp1[d], wvv = wp2[d];
#pragma unroll
            for (int r = 0; r < 4; r++) {
                float hv = acc[r] + bpv;
                hv = (hv >= 0.f) ? hv : 0.01f * hv;
                dgp[r] = fmaf(hv, wvv, dgp[r]);
            }
        }
    }
#pragma unroll
    for (int r = 0; r < 4; r++) {
        float v = dgp[r];
        v += __shfl_xor(v, 1); v += __shfl_xor(v, 2);
        v += __shfl_xor(v, 4); v += __shfl_xor(v, 8);
        dgp[r] = v;
    }
    if (lr == 0) {
        float b2 = bp2[0];
        int bh = b * 16 + h;
#pragma unroll
        for (int r = 0; r < 4; r++)
            DG[(size_t)bh*512 + lt*64 + w*16 + kg*4 + r] = dgp[r] + b2;
    }
}

// alpha = softmax_k(dot_gamma); accumulate alpha-only KL terms into acc[2]
__global__ __launch_bounds__(512) void k_alpha(
    const float* __restrict__ DG, float* __restrict__ AL, double* __restrict__ acc)
{
    __shared__ float red[512];
    const int bh = blockIdx.x, t = threadIdx.x;
    float v = DG[(size_t)bh * 512 + t];
    red[t] = v; __syncthreads();
    for (int s = 256; s > 0; s >>= 1) { if (t < s) red[t] = fmaxf(red[t], red[t+s]); __syncthreads(); }
    float m = red[0]; __syncthreads();
    float e = expf(v - m);
    red[t] = e; __syncthreads();
    for (int s = 256; s > 0; s >>= 1) { if (t < s) red[t] += red[t+s]; __syncthreads(); }
    float ssum = red[0]; __syncthreads();
    float a = e / ssum;                 // * BETA_GAMMA (=1)
    AL[(size_t)bh * 512 + t] = a;
    // lg1 + 2*eulergamma = 0.6931471805599453 + 1.1544313298030658
    float t2 = a * 1.8475785103630112f + lgammaf(a + 1e-20f);
    red[t] = t2; __syncthreads();
    for (int s = 256; s > 0; s >>= 1) { if (t < s) red[t] += red[t+s]; __syncthreads(); }
    if (t == 0) atomicAdd(&acc[2], (double)red[0]);
}

// fused stochastic attention: one block per (b,h, 64-row q-chunk)
// pass A: QK split-MFMA + online (M1,Z1) + G chain -> fp16 spill (interleaved)
// pass B: K-restage + 3-MFMA logit recompute + exp/log + softmax-2 + PV
//         (V direct from global VT; Sl overlaid into KtL behind 3rd barrier)
__global__ __launch_bounds__(256, 6) void k_attn(
    const bh_t* __restrict__ QH, const bh_t* __restrict__ QL,
    const bh_t* __restrict__ KH, const bh_t* __restrict__ KL,
    const bh_t* __restrict__ VT, const float* __restrict__ U,
    const float* __restrict__ AL, bh_t* __restrict__ HOB,
    hf_t* __restrict__ GS, double* __restrict__ acc)
{
    __shared__ __align__(16) bh_t KtH[64][72];
    __shared__ __align__(16) bh_t KtL[64][72];   // PV phase: wave-sliced Sl overlay
    __shared__ float Asm[64];
    __shared__ float red[256];

    const int flat = blockIdx.x;
    const int bh = flat & 127, qc = flat >> 7;   // 8 q-chunks of one bh share an XCD
    const int b = bh >> 4, h = bh & 15;
    const int t = threadIdx.x, w = t >> 6, lane = t & 63;
    const int lr = lane & 15, kg = lane >> 4;
    const int q0 = qc * 64 + w * 16;
    const int sr = t >> 2, sj = (t & 3) * 16;
    const float* Up = U + ((size_t)bh * 512 + q0 + kg * 4) * 512;
    hf_t* GSp = GS + (size_t)flat * 32768 + (size_t)w * 8192;

    bh8 qh[2], ql[2];
    {
        size_t qb = ((size_t)(b * 512) + q0 + lr) * 1024 + h * 64;
        qh[0] = *(const bh8*)(QH + qb + kg * 8);
        qh[1] = *(const bh8*)(QH + qb + 32 + kg * 8);
        ql[0] = *(const bh8*)(QL + qb + kg * 8);
        ql[1] = *(const bh8*)(QL + qb + 32 + kg * 8);
    }
    float C[4];   // per-q-row M1 + lnZ1, carried A -> B

    // ---- pass A: logits (split-bf16 MFMA), G chain + fp16 spill, M1/Z1 ----
    {
        float M1[4], Z1[4];
#pragma unroll
        for (int r = 0; r < 4; r++) { M1[r] = -INFINITY; Z1[r] = 0.f; }

        for (int kt = 0; kt < 8; kt++) {
            __syncthreads();
            {
                size_t src = ((size_t)(b*512 + kt*64 + sr)) * 1024 + h*64 + sj;
                *(bh8*)&KtH[sr][sj]     = *(const bh8*)(KH + src);
                *(bh8*)&KtH[sr][sj + 8] = *(const bh8*)(KH + src + 8);
                *(bh8*)&KtL[sr][sj]     = *(const bh8*)(KL + src);
                *(bh8*)&KtL[sr][sj + 8] = *(const bh8*)(KL + src + 8);
            }
            __syncthreads();
            f32x4 av[4];
#pragma unroll
            for (int fn = 0; fn < 4; fn++) {
                f32x4 a = {};
#pragma unroll
                for (int ks = 0; ks < 2; ks++) {
                    bh8 kb  = *(bh8*)&KtH[fn*16 + lr][ks*32 + kg*8];
                    bh8 kl2 = *(bh8*)&KtL[fn*16 + lr][ks*32 + kg*8];
                    a = MFMA_BF16(qh[ks], kb,  a, 0, 0, 0);
                    a = MFMA_BF16(qh[ks], kl2, a, 0, 0, 0);
                    a = MFMA_BF16(ql[ks], kb,  a, 0, 0, 0);
                }
#pragma unroll
                for (int r = 0; r < 4; r++) a[r] *= 8.0f;   // att / SCALE, SCALE=1/8
                av[fn] = a;
                // Gumbel/lgamma chain — independent of the MFMAs above, fills
                // their latency; spill G (fp16) in fragment layout.
                int k = kt * 64 + fn * 16 + lr;
                hf4 gh;
#pragma unroll
                for (int r = 0; r < 4; r++) {
                    float u  = Up[(size_t)r * 512 + k];
                    float tt = (1.0f - u) + 1e-20f;
                    float gl = 1e-20f - __logf(tt);
                    float g  = __logf(gl);
                    gh[r] = (hf_t)lgamma_fast(fmaf(2.0f, g, 3.0f)); // 1+1/k+(1/k)*gumbel
                }
                *(hf4*)(GSp + ((size_t)(kt*4 + fn) * 64 + lane) * 4) = gh;
            }
#pragma unroll
            for (int r = 0; r < 4; r++) {
                float mx = fmaxf(fmaxf(av[0][r], av[1][r]), fmaxf(av[2][r], av[3][r]));
                mx = fmaxf(mx, __shfl_xor(mx, 1));
                mx = fmaxf(mx, __shfl_xor(mx, 2));
                mx = fmaxf(mx, __shfl_xor(mx, 4));
                mx = fmaxf(mx, __shfl_xor(mx, 8));
                float nm = fmaxf(M1[r], mx);
                float es = __expf(av[0][r]-nm) + __expf(av[1][r]-nm)
                         + __expf(av[2][r]-nm) + __expf(av[3][r]-nm);
                es += __shfl_xor(es, 1); es += __shfl_xor(es, 2);
                es += __shfl_xor(es, 4); es += __shfl_xor(es, 8);
                Z1[r] = Z1[r] * __expf(M1[r] - nm) + es;
                M1[r] = nm;
            }
        }
#pragma unroll
        for (int r = 0; r < 4; r++) C[r] = M1[r] + logf(Z1[r]);
    }

    // ---- pass B: restage K; recompute s; lp + spilled G; softmax-2 + PV ----
    bh_t (*SlK)[72] = (bh_t(*)[72])(&KtL[w*16][0]);  // per-wave 16-row slice
    float M2[4], Z2[4];
    f32x4 oacc[4] = {};
#pragma unroll
    for (int r = 0; r < 4; r++) { M2[r] = -INFINITY; Z2[r] = 0.f; }
    float S1f = 0.f;
    const bh_t* Vb = VT + (size_t)bh * 64 * 512;

    for (int kt = 0; kt < 8; kt++) {
        __syncthreads();   // (1) prior iter's Sl/K reads done before restage
        {
            size_t src = ((size_t)(b*512 + kt*64 + sr)) * 1024 + h*64 + sj;
            *(bh8*)&KtH[sr][sj]     = *(const bh8*)(KH + src);
            *(bh8*)&KtH[sr][sj + 8] = *(const bh8*)(KH + src + 8);
            *(bh8*)&KtL[sr][sj]     = *(const bh8*)(KL + src);
            *(bh8*)&KtL[sr][sj + 8] = *(const bh8*)(KL + src + 8);
            if (t < 64) Asm[t] = AL[(size_t)bh * 512 + kt * 64 + t];
        }
        __syncthreads();   // (2) staged
        f32x4 wv[4];
#pragma unroll
        for (int fn = 0; fn < 4; fn++) {
            f32x4 a = {};
#pragma unroll
            for (int ks = 0; ks < 2; ks++) {
                bh8 kb  = *(bh8*)&KtH[fn*16 + lr][ks*32 + kg*8];
                bh8 kl2 = *(bh8*)&KtL[fn*16 + lr][ks*32 + kg*8];
                a = MFMA_BF16(qh[ks], kb,  a, 0, 0, 0);
                a = MFMA_BF16(qh[ks], kl2, a, 0, 0, 0);
                a = MFMA_BF16(ql[ks], kb,  a, 0, 0, 0);
            }
            hf4 gh = *(const hf4*)(GSp + ((size_t)(kt*4 + fn) * 64 + lane) * 4);
            float alv = Asm[fn * 16 + lr];
#pragma unroll
            for (int r = 0; r < 4; r++) {
                float s  = fmaf(a[r], 8.0f, -C[r]);      // logit - (M1+lnZ1)
                float ex = __expf(s);                     // = softmax-1 prob
                float lp = __logf(ex + 1e-20f);           // exact EPS-floor
                wv[fn][r] = lp - (float)gh[r];
                S1f = fmaf(alv, lp, S1f);
            }
        }
        __syncthreads();   // (3) all waves' KtL fragment reads done -> Sl overlay safe
#pragma unroll
        for (int r = 0; r < 4; r++) {
            float mx = fmaxf(fmaxf(wv[0][r], wv[1][r]), fmaxf(wv[2][r], wv[3][r]));
            mx = fmaxf(mx, __shfl_xor(mx, 1));
            mx = fmaxf(mx, __shfl_xor(mx, 2));
            mx = fmaxf(mx, __shfl_xor(mx, 4));
            mx = fmaxf(mx, __shfl_xor(mx, 8));
            float nm = fmaxf(M2[r], mx);
            float sc = __expf(M2[r] - nm);               // exp(-inf)=0, exp(0)=1
            float zs = 0.f;
#pragma unroll
            for (int fn = 0; fn < 4; fn++) {
                float sv = __expf(wv[fn][r] - nm);
                zs += sv;
                SlK[kg * 4 + r][fn * 16 + lr] = (bh_t)sv;
            }
            zs += __shfl_xor(zs, 1); zs += __shfl_xor(zs, 2);
            zs += __shfl_xor(zs, 4); zs += __shfl_xor(zs, 8);
            Z2[r] = fmaf(Z2[r], sc, zs);
            M2[r] = nm;
#pragma unroll
            for (int fo = 0; fo < 4; fo++) oacc[fo][r] *= sc;
        }
        // Sl slice is per-wave: same-wave LDS write->read is program-ordered.
        bh8 sa0 = *(bh8*)&SlK[lr][kg*8];
        bh8 sa1 = *(bh8*)&SlK[lr][32 + kg*8];
#pragma unroll
        for (int fo = 0; fo < 4; fo++) {
            const bh_t* vr = Vb + (size_t)(fo*16 + lr) * 512 + kt*64;
            bh8 v0 = *(const bh8*)(vr + kg*8);
            bh8 v1 = *(const bh8*)(vr + 32 + kg*8);
            oacc[fo] = MFMA_BF16(sa0, v0, oacc[fo], 0, 0, 0);
            oacc[fo] = MFMA_BF16(sa1, v1, oacc[fo], 0, 0, 0);
        }
    }
    float rz[4];
#pragma unroll
    for (int r = 0; r < 4; r++) rz[r] = 1.0f / Z2[r];
    // head output (bf16): HO[b, q, h*64+dv]
#pragma unroll
    for (int fo = 0; fo < 4; fo++) {
#pragma unroll
        for (int r = 0; r < 4; r++) {
            int q = q0 + kg * 4 + r;
            int dv = fo * 16 + lr;
            HOB[((size_t)(b * 512 + q)) * 1024 + h * 64 + dv] = (bh_t)(oacc[fo][r] * rz[r]);
        }
    }
    red[t] = S1f; __syncthreads();
    for (int s = 128; s > 0; s >>= 1) { if (t < s) red[t] += red[t+s]; __syncthreads(); }
    if (t == 0) atomicAdd(&acc[0], (double)red[0]);
}

__global__ void k_kl(const double* __restrict__ acc, float* __restrict__ out)
{
    if (threadIdx.x == 0 && blockIdx.x == 0) {
        // S2 = sum(exp(log(softmax+1e-20))) = B*H*L (+ BHL*L*1e-20, negligible)
        double kl = (-acc[0] + 512.0 * acc[2] + 65536.0) / 33554432.0;
        out[4194304] = (float)kl;
    }
}

// ---------------------------------------------------------------------------
extern "C" void kernel_launch(void* const* d_in, const int* in_sizes, int n_in,
                              void* d_out, int out_size, void* d_ws, size_t ws_size,
                              hipStream_t stream)
{
    (void)in_sizes; (void)n_in; (void)d_ws; (void)ws_size; (void)out_size;
    const float* queries = (const float*)d_in[0];
    const float* keys    = (const float*)d_in[1];
    const float* values  = (const float*)d_in[2];
    const float* unif    = (const float*)d_in[3];
    const float* Wq = (const float*)d_in[4];  const float* bq = (const float*)d_in[5];
    const float* Wk = (const float*)d_in[6];  const float* bk = (const float*)d_in[7];
    const float* Wv = (const float*)d_in[8];  const float* bv = (const float*)d_in[9];
    const float* Wo = (const float*)d_in[10]; const float* bo = (const float*)d_in[11];
    const float* Wp1 = (const float*)d_in[12]; const float* bp1 = (const float*)d_in[13];
    const float* Wp2 = (const float*)d_in[14]; const float* bp2 = (const float*)d_in[15];

    unsigned char* ws = nullptr;
    hipGetSymbolAddress((void**)&ws, HIP_SYMBOL(g_ws));

    bh_t* QHI = (bh_t*)(ws + O_QHI); bh_t* QLO = (bh_t*)(ws + O_QLO);
    bh_t* KHI = (bh_t*)(ws + O_KHI); bh_t* KLO = (bh_t*)(ws + O_KLO);
    bh_t* VBp = (bh_t*)(ws + O_VB);  bh_t* VTp = (bh_t*)(ws + O_VT);
    bh_t* WQH = (bh_t*)(ws + O_WQH); bh_t* WQL = (bh_t*)(ws + O_WQL);
    bh_t* WKH = (bh_t*)(ws + O_WKH); bh_t* WKL = (bh_t*)(ws + O_WKL);
    bh_t* WVH = (bh_t*)(ws + O_WVH); bh_t* WVL = (bh_t*)(ws + O_WVL);
    bh_t* WOH = (bh_t*)(ws + O_WOH); bh_t* WOL = (bh_t*)(ws + O_WOL);
    bh_t* WP1H = (bh_t*)(ws + O_WP1H); bh_t* WP1L = (bh_t*)(ws + O_WP1L);
    float* DG    = (float*)(ws + O_DG);
    float* ALPHA = (float*)(ws + O_ALPHA);
    bh_t*  HOB   = (bh_t*)(ws + O_HO);
    hf_t*  GS    = (hf_t*)(ws + O_GS);
    double* ACC  = (double*)(ws + O_ACC);
    float* outF  = (float*)d_out;

    k_zero<<<1, 64, 0, stream>>>(ACC);

    k_transpose_split<<<dim3(16,16), 256, 0, stream>>>(Wq,  WQH,  WQL, 1024, 1024);
    k_transpose_split<<<dim3(16,16), 256, 0, stream>>>(Wk,  WKH,  WKL, 1024, 1024);
    k_transpose_split<<<dim3(16,16), 256, 0, stream>>>(Wv,  WVH,  WVL, 1024, 1024);
    k_transpose_split<<<dim3(16,16), 256, 0, stream>>>(Wo,  WOH,  WOL, 1024, 1024);
    k_transpose_split<<<dim3(16,1),  256, 0, stream>>>(Wp1, WP1H, WP1L, 64, 1024);

    k_gemm<true, 0,false><<<dim3(16,64), 256, 0, stream>>>(queries, nullptr, WQH, WQL, bq, QHI, QLO, nullptr);
    k_gemm<true, 0,false><<<dim3(16,64), 256, 0, stream>>>(keys,    nullptr, WKH, WKL, bk, KHI, KLO, nullptr);
    k_gemm<false,1,false><<<dim3(16,64), 256, 0, stream>>>(values,  nullptr, WVH, WVL, bv, VBp, nullptr, nullptr);

    k_transV<<<dim3(8,16,8), 256, 0, stream>>>(VBp, VTp);
    k_prior<<<dim3(8,16,8), 256, 0, stream>>>(KHI, WP1H, bp1, Wp2, bp2, DG);
    k_alpha<<<128, 512, 0, stream>>>(DG, ALPHA, ACC);

    k_attn<<<1024, 256, 0, stream>>>(QHI, QLO, KHI, KLO, VTp, unif, ALPHA, HOB, GS, ACC);

    k_gemm<false,2,true><<<dim3(16,64), 256, 0, stream>>>(nullptr, HOB, WOH, WOL, bo, nullptr, nullptr, outF);
    k_kl<<<1, 1, 0, stream>>>(ACC, outF);
}

// Round 10
// 362.623 us; speedup vs baseline: 1.3966x; 1.2907x over previous
//
#include <hip/hip_runtime.h>
#include <math.h>

// ---------------------------------------------------------------------------
// BayesianAttention (B=8, L=512, D=1024, H=16, DK=DV=64, k_weibull=0.5)
// Numerics plan:
//   - Q/K projections + QK^T: split-bf16 (hi/lo) 3-MFMA => ~fp32-ish precision
//   - V projection, prior MLP, PV, output GEMM: plain bf16 MFMA
//   - k_attn = R7 structure (proven 211us) + QBLK=128 (512 thr, 8 waves,
//     same per-wave code; LDS 48.4KB -> 3 blocks/CU = 24 waves = 75% occ)
//     + fp16 G-spill (validated R9: absmax unchanged, traffic halved):
//       pass A: QK MFMA + online (M1,Z1) + Gumbel/lgamma G chain interleaved
//               (fills MFMA latency), G spilled fp16 (64 MB arena)
//       pass B: K-restage + 3-MFMA logit recompute + exp/log + softmax-2 + PV
//               with LDS-staged Vt (two barriers per k-tile, no extra sync)
//   - V-transpose fused into V-GEMM epilogue (OMODE 3 writes VT directly)
//   - EPS-floor lp = log(exp(s-C)+1e-20) kept exact (load-bearing tail)
//   - S2 = sum exp(log(softmax+1e-20)) = B*H*L exactly -> constant in k_kl
//   - KL: kl_mean = (-S1 + L*T2 + S2) / (B*H*L*L)
// ---------------------------------------------------------------------------

typedef __bf16 bh_t;
typedef bh_t  bh8  __attribute__((ext_vector_type(8)));
typedef float f32x4 __attribute__((ext_vector_type(4)));
typedef _Float16 hf_t;
typedef hf_t  hf4  __attribute__((ext_vector_type(4)));

#define MFMA_BF16 __builtin_amdgcn_mfma_f32_16x16x32_bf16

// ---- scratch layout in a device-global arena (no dependence on ws_size) ----
static constexpr size_t P2 = 4096ull*1024ull*2ull;   // bf16 [4096][1024] plane
static constexpr size_t W2 = 1024ull*1024ull*2ull;   // bf16 [1024][1024] plane
static constexpr size_t O_QHI = 0;
static constexpr size_t O_QLO = O_QHI + P2;
static constexpr size_t O_KHI = O_QLO + P2;
static constexpr size_t O_KLO = O_KHI + P2;
static constexpr size_t O_VT  = O_KLO + P2;          // bf16 [128][64][512] V^T
static constexpr size_t O_WQH = O_VT  + P2;          // 4x {hi,lo} contiguous
static constexpr size_t O_WQL = O_WQH + W2;
static constexpr size_t O_WKH = O_WQL + W2;
static constexpr size_t O_WKL = O_WKH + W2;
static constexpr size_t O_WVH = O_WKL + W2;
static constexpr size_t O_WVL = O_WVH + W2;
static constexpr size_t O_WOH = O_WVL + W2;
static constexpr size_t O_WOL = O_WOH + W2;
static constexpr size_t O_WP1H = O_WOL + W2;
static constexpr size_t O_WP1L = O_WP1H + 1024ull*64ull*2ull;
static constexpr size_t O_DG   = O_WP1L + 1024ull*64ull*2ull;
static constexpr size_t O_ALPHA= O_DG + 65536ull*4ull;
static constexpr size_t O_HO   = O_ALPHA + 65536ull*4ull;               // bf16 [4096][1024]
static constexpr size_t O_GS   = O_HO + P2;                             // fp16 G spill, 64 MB
static constexpr size_t O_ACC  = O_GS + 512ull*65536ull*2ull;           // 3 doubles
static constexpr size_t WS_TOTAL = O_ACC + 256;

__device__ __align__(256) unsigned char g_ws[WS_TOTAL];

// ---------------------------------------------------------------------------
// slim lgamma: reflection + shift-to-(>=4) + 2-term Stirling, all hw trans.
// abs err ~1e-5 away from poles; poles only where weight -> 0 / ref is inf too.
__device__ __forceinline__ float lgamma_fast(float x)
{
    float ax = (x < 0.5f) ? (1.0f - x) : x;          // ax >= 0.5
    float p  = ax*(ax+1.f)*(ax+2.f)*(ax+3.f);
    bool  sm = ax < 4.0f;
    float lsh = sm ? __logf(p) : 0.0f;
    float y   = sm ? (ax + 4.0f) : ax;               // y >= 4
    float ly  = __logf(y);
    float inv = __builtin_amdgcn_rcpf(y);
    float i2  = inv * inv;
    float stir = fmaf(y - 0.5f, ly, -y) + 0.91893853320467274f
               + inv * fmaf(-2.7777777777e-3f, i2, 8.3333333333e-2f);
    float core = stir - lsh;                         // lgamma(ax)
    // reflection: lgamma(x) = ln(pi) - ln|sin(pi x)| - lgamma(1-x)
    float r  = x - rintf(x);                         // |r| <= 0.5
    float sp = __sinf(3.14159265358979f * r);
    float rres = 1.14472988584940017f - __logf(fabsf(sp)) - core;
    return (x < 0.5f) ? rres : core;
}

// ---------------------------------------------------------------------------
__global__ void k_zero(double* a)
{
    if (threadIdx.x < 4) a[threadIdx.x] = 0.0;
}

// transpose f32 [rows][cols] -> bf16 hi/lo [cols][rows] (single matrix)
__global__ __launch_bounds__(256) void k_transpose_split(
    const float* __restrict__ in, bh_t* __restrict__ oh, bh_t* __restrict__ ol,
    int rows, int cols)
{
    __shared__ float tile[64][65];
    const int bc = blockIdx.x * 64, br = blockIdx.y * 64;
    const int t = threadIdx.x;
    const int r = t >> 2, c0 = (t & 3) * 16;
#pragma unroll
    for (int i = 0; i < 16; i += 4) {
        float4 v = *(const float4*)(in + (size_t)(br + r) * cols + bc + c0 + i);
        tile[r][c0+i]   = v.x; tile[r][c0+i+1] = v.y;
        tile[r][c0+i+2] = v.z; tile[r][c0+i+3] = v.w;
    }
    __syncthreads();
    bh8 hv[2], lv[2];
#pragma unroll
    for (int i = 0; i < 16; i++) {
        float x = tile[c0 + i][r];
        bh_t hh = (bh_t)x;
        hv[i >> 3][i & 7] = hh;
        lv[i >> 3][i & 7] = (bh_t)(x - (float)hh);
    }
    size_t ob = (size_t)(bc + r) * rows + br + c0;
    *(bh8*)(oh + ob)     = hv[0];
    *(bh8*)(oh + ob + 8) = hv[1];
    *(bh8*)(ol + ob)     = lv[0];
    *(bh8*)(ol + ob + 8) = lv[1];
}

// fused: transpose+split all four 1024x1024 weights (z selects matrix);
// dst planes are contiguous in the arena: [z][hi|lo] each 1024*1024 bf16.
__global__ __launch_bounds__(256) void k_transpose_split4(
    const float* __restrict__ W0, const float* __restrict__ W1,
    const float* __restrict__ W2_, const float* __restrict__ W3,
    bh_t* __restrict__ OH)
{
    __shared__ float tile[64][65];
    const int z = blockIdx.z;
    const float* in = (z == 0) ? W0 : (z == 1) ? W1 : (z == 2) ? W2_ : W3;
    bh_t* oh = OH + (size_t)z * 2ull * 1024ull * 1024ull;
    bh_t* ol = oh + 1024ull * 1024ull;
    const int bc = blockIdx.x * 64, br = blockIdx.y * 64;
    const int t = threadIdx.x;
    const int r = t >> 2, c0 = (t & 3) * 16;
#pragma unroll
    for (int i = 0; i < 16; i += 4) {
        float4 v = *(const float4*)(in + (size_t)(br + r) * 1024 + bc + c0 + i);
        tile[r][c0+i]   = v.x; tile[r][c0+i+1] = v.y;
        tile[r][c0+i+2] = v.z; tile[r][c0+i+3] = v.w;
    }
    __syncthreads();
    bh8 hv[2], lv[2];
#pragma unroll
    for (int i = 0; i < 16; i++) {
        float x = tile[c0 + i][r];
        bh_t hh = (bh_t)x;
        hv[i >> 3][i & 7] = hh;
        lv[i >> 3][i & 7] = (bh_t)(x - (float)hh);
    }
    size_t ob = (size_t)(bc + r) * 1024 + br + c0;
    *(bh8*)(oh + ob)     = hv[0];
    *(bh8*)(oh + ob + 8) = hv[1];
    *(bh8*)(ol + ob)     = lv[0];
    *(bh8*)(ol + ob + 8) = lv[1];
}

// C[4096][1024] = A[4096][1024] @ W[1024][1024] + bias
// A: f32 (ABF=0, converted inline) or pre-converted bf16 plane (ABF=1).
// W pre-transposed bf16 hi/lo planes [n][k].
// OMODE 0: bf16 hi+lo planes; 1: bf16 plane; 2: f32; 3: bf16 into VT layout.
template<bool SPLIT, int OMODE, bool ABF>
__global__ __launch_bounds__(256) void k_gemm(
    const float* __restrict__ A, const bh_t* __restrict__ ABH,
    const bh_t* __restrict__ WH, const bh_t* __restrict__ WL,
    const float* __restrict__ bias,
    bh_t* __restrict__ oh, bh_t* __restrict__ ol, float* __restrict__ of)
{
    __shared__ __align__(16) bh_t Ah[64][40];
    __shared__ __align__(16) bh_t Al[64][40];
    __shared__ __align__(16) bh_t Bh[64][40];
    __shared__ __align__(16) bh_t Bl[64][40];
    const int n0 = blockIdx.x * 64, m0 = blockIdx.y * 64;
    const int t = threadIdx.x;
    const int lane = t & 63, w = t >> 6;
    const int lr = lane & 15, kg = lane >> 4;
    const int wm = (w & 1) * 32, wn = (w >> 1) * 32;
    const int ar = t >> 2, ac = (t & 3) * 8;
    f32x4 acc[2][2] = {};

    for (int kt = 0; kt < 1024; kt += 32) {
        __syncthreads();
        {
            if constexpr (ABF) {
                *(bh8*)&Ah[ar][ac] = *(const bh8*)(ABH + (size_t)(m0 + ar) * 1024 + kt + ac);
            } else {
                const float* ap = A + (size_t)(m0 + ar) * 1024 + kt + ac;
                float4 v0 = *(const float4*)ap;
                float4 v1 = *(const float4*)(ap + 4);
                float xs[8] = {v0.x, v0.y, v0.z, v0.w, v1.x, v1.y, v1.z, v1.w};
                bh8 h, l;
#pragma unroll
                for (int i = 0; i < 8; i++) {
                    bh_t hh = (bh_t)xs[i];
                    h[i] = hh;
                    l[i] = (bh_t)(xs[i] - (float)hh);
                }
                *(bh8*)&Ah[ar][ac] = h;
                if constexpr (SPLIT) *(bh8*)&Al[ar][ac] = l;
            }
            size_t wb = (size_t)(n0 + ar) * 1024 + kt + ac;
            *(bh8*)&Bh[ar][ac] = *(const bh8*)(WH + wb);
            if constexpr (SPLIT) *(bh8*)&Bl[ar][ac] = *(const bh8*)(WL + wb);
        }
        __syncthreads();
#pragma unroll
        for (int fm = 0; fm < 2; fm++) {
            bh8 a_h = *(bh8*)&Ah[wm + fm*16 + lr][kg * 8];
#pragma unroll
            for (int fn = 0; fn < 2; fn++) {
                bh8 b_h = *(bh8*)&Bh[wn + fn*16 + lr][kg * 8];
                acc[fm][fn] = MFMA_BF16(a_h, b_h, acc[fm][fn], 0, 0, 0);
                if constexpr (SPLIT) {
                    bh8 a_l = *(bh8*)&Al[wm + fm*16 + lr][kg * 8];
                    bh8 b_l = *(bh8*)&Bl[wn + fn*16 + lr][kg * 8];
                    acc[fm][fn] = MFMA_BF16(a_h, b_l, acc[fm][fn], 0, 0, 0);
                    acc[fm][fn] = MFMA_BF16(a_l, b_h, acc[fm][fn], 0, 0, 0);
                }
            }
        }
    }
#pragma unroll
    for (int fm = 0; fm < 2; fm++)
#pragma unroll
    for (int fn = 0; fn < 2; fn++) {
        int col = n0 + wn + fn*16 + lr;
        float bv = bias[col];
#pragma unroll
        for (int r = 0; r < 4; r++) {
            int row = m0 + wm + fm*16 + kg*4 + r;
            float c = acc[fm][fn][r] + bv;
            size_t idx = (size_t)row * 1024 + col;
            if constexpr (OMODE == 0) {
                bh_t hh = (bh_t)c;
                oh[idx] = hh;
                ol[idx] = (bh_t)(c - (float)hh);
            } else if constexpr (OMODE == 1) {
                oh[idx] = (bh_t)c;
            } else if constexpr (OMODE == 2) {
                of[idx] = c;
            } else {
                // VT layout: [(b*16+h)*64+dv][l], h=col>>6, dv=col&63
                int bb = row >> 9, ll = row & 511;
                oh[(((size_t)(bb*16 + (col >> 6)) * 64) + (col & 63)) * 512 + ll] = (bh_t)c;
            }
        }
    }
}

// dot_gamma[b,h,l] = Wp2 . leakyrelu(K_head[b,h,l,:] @ Wp1 + bp1) + bp2
__global__ __launch_bounds__(256) void k_prior(
    const bh_t* __restrict__ KH, const bh_t* __restrict__ WP1T,
    const float* __restrict__ bp1, const float* __restrict__ wp2,
    const float* __restrict__ bp2, float* __restrict__ DG)
{
    __shared__ __align__(16) bh_t Kt[64][72];
    __shared__ __align__(16) bh_t Wt[64][72];
    const int lt = blockIdx.x, h = blockIdx.y, b = blockIdx.z;
    const int t = threadIdx.x, lane = t & 63, w = t >> 6;
    const int lr = lane & 15, kg = lane >> 4;
    {
        int r = t >> 2, j0 = (t & 3) * 16;
        const bh_t* src = KH + ((size_t)(b*512 + lt*64 + r)) * 1024 + h*64 + j0;
        *(bh8*)&Kt[r][j0]     = *(const bh8*)src;
        *(bh8*)&Kt[r][j0 + 8] = *(const bh8*)(src + 8);
    }
    __syncthreads();
    bh8 af0 = *(bh8*)&Kt[w*16 + lr][kg * 8];
    bh8 af1 = *(bh8*)&Kt[w*16 + lr][32 + kg * 8];
    float dgp[4] = {0.f, 0.f, 0.f, 0.f};
    for (int dt = 0; dt < 16; dt++) {
        __syncthreads();
        {
            int r = t >> 2, j0 = (t & 3) * 16;
            const bh_t* src = WP1T + (size_t)(dt*64 + r) * 64 + j0;
            *(bh8*)&Wt[r][j0]     = *(const bh8*)src;
            *(bh8*)&Wt[r][j0 + 8] = *(const bh8*)(src + 8);
        }
        __syncthreads();
#pragma unroll
        for (int fn = 0; fn < 4; fn++) {
            bh8 b0 = *(bh8*)&Wt[fn*16 + lr][kg * 8];
            bh8 b1 = *(bh8*)&Wt[fn*16 + lr][32 + kg * 8];
            f32x4 acc = {};
            acc = MFMA_BF16(af0, b0, acc, 0, 0, 0);
            acc = MFMA_BF16(af1, b1, acc, 0, 0, 0);
            int d = dt*64 + fn*16 + lr;
            float bpv = bp1[d], wvv = wp2[d];
#pragma unroll
            for (int r = 0; r < 4; r++) {
                float hv = acc[r] + bpv;
                hv = (hv >= 0.f) ? hv : 0.01f * hv;
                dgp[r] = fmaf(hv, wvv, dgp[r]);
            }
        }
    }
#pragma unroll
    for (int r = 0; r < 4; r++) {
        float v = dgp[r];
        v += __shfl_xor(v, 1); v += __shfl_xor(v, 2);
        v += __shfl_xor(v, 4); v += __shfl_xor(v, 8);
        dgp[r] = v;
    }
    if (lr == 0) {
        float b2 = bp2[0];
        int bh = b * 16 + h;
#pragma unroll
        for (int r = 0; r < 4; r++)
            DG[(size_t)bh*512 + lt*64 + w*16 + kg*4 + r] = dgp[r] + b2;
    }
}

// alpha = softmax_k(dot_gamma); accumulate alpha-only KL terms into acc[2]
__global__ __launch_bounds__(512) void k_alpha(
    const float* __restrict__ DG, float* __restrict__ AL, double* __restrict__ acc)
{
    __shared__ float red[512];
    const int bh = blockIdx.x, t = threadIdx.x;
    float v = DG[(size_t)bh * 512 + t];
    red[t] = v; __syncthreads();
    for (int s = 256; s > 0; s >>= 1) { if (t < s) red[t] = fmaxf(red[t], red[t+s]); __syncthreads(); }
    float m = red[0]; __syncthreads();
    float e = expf(v - m);
    red[t] = e; __syncthreads();
    for (int s = 256; s > 0; s >>= 1) { if (t < s) red[t] += red[t+s]; __syncthreads(); }
    float ssum = red[0]; __syncthreads();
    float a = e / ssum;                 // * BETA_GAMMA (=1)
    AL[(size_t)bh * 512 + t] = a;
    // lg1 + 2*eulergamma = 0.6931471805599453 + 1.1544313298030658
    float t2 = a * 1.8475785103630112f + lgammaf(a + 1e-20f);
    red[t] = t2; __syncthreads();
    for (int s = 256; s > 0; s >>= 1) { if (t < s) red[t] += red[t+s]; __syncthreads(); }
    if (t == 0) atomicAdd(&acc[2], (double)red[0]);
}

// fused stochastic attention: one block per (b,h, 128-row q-chunk), 8 waves.
// pass A: QK split-MFMA + online (M1,Z1) + G chain -> fp16 spill (interleaved)
// pass B: K-restage + 3-MFMA logit recompute + exp/log + softmax-2 + PV (Vt LDS)
__global__ __launch_bounds__(512, 3) void k_attn(
    const bh_t* __restrict__ QH, const bh_t* __restrict__ QL,
    const bh_t* __restrict__ KH, const bh_t* __restrict__ KL,
    const bh_t* __restrict__ VT, const float* __restrict__ U,
    const float* __restrict__ AL, bh_t* __restrict__ HOB,
    hf_t* __restrict__ GS, double* __restrict__ acc)
{
    __shared__ __align__(16) bh_t KtH[64][72];
    __shared__ __align__(16) bh_t KtL[64][72];
    __shared__ __align__(16) bh_t Vt[64][72];
    __shared__ __align__(16) bh_t Sl[8][16][72];
    __shared__ float Asm[64];
    __shared__ float red[512];

    const int flat = blockIdx.x;
    const int bh = flat & 127, qc = flat >> 7;   // 4 q-chunks of one bh share an XCD
    const int b = bh >> 4, h = bh & 15;
    const int t = threadIdx.x, w = t >> 6, lane = t & 63;
    const int lr = lane & 15, kg = lane >> 4;
    const int q0 = qc * 128 + w * 16;
    const int sr = t >> 3, sj = (t & 7) * 8;
    const float* Up = U + ((size_t)bh * 512 + q0 + kg * 4) * 512;
    hf_t* GSp = GS + (size_t)flat * 65536 + (size_t)w * 8192;

    bh8 qh[2], ql[2];
    {
        size_t qb = ((size_t)(b * 512) + q0 + lr) * 1024 + h * 64;
        qh[0] = *(const bh8*)(QH + qb + kg * 8);
        qh[1] = *(const bh8*)(QH + qb + 32 + kg * 8);
        ql[0] = *(const bh8*)(QL + qb + kg * 8);
        ql[1] = *(const bh8*)(QL + qb + 32 + kg * 8);
    }
    float C[4];   // per-q-row M1 + lnZ1, carried A -> B

    // ---- pass A: logits (split-bf16 MFMA), G chain + fp16 spill, M1/Z1 ----
    {
        float M1[4], Z1[4];
#pragma unroll
        for (int r = 0; r < 4; r++) { M1[r] = -INFINITY; Z1[r] = 0.f; }

        for (int kt = 0; kt < 8; kt++) {
            __syncthreads();
            {
                size_t src = ((size_t)(b*512 + kt*64 + sr)) * 1024 + h*64 + sj;
                *(bh8*)&KtH[sr][sj] = *(const bh8*)(KH + src);
                *(bh8*)&KtL[sr][sj] = *(const bh8*)(KL + src);
            }
            __syncthreads();
            f32x4 av[4];
#pragma unroll
            for (int fn = 0; fn < 4; fn++) {
                f32x4 a = {};
#pragma unroll
                for (int ks = 0; ks < 2; ks++) {
                    bh8 kb  = *(bh8*)&KtH[fn*16 + lr][ks*32 + kg*8];
                    bh8 kl2 = *(bh8*)&KtL[fn*16 + lr][ks*32 + kg*8];
                    a = MFMA_BF16(qh[ks], kb,  a, 0, 0, 0);
                    a = MFMA_BF16(qh[ks], kl2, a, 0, 0, 0);
                    a = MFMA_BF16(ql[ks], kb,  a, 0, 0, 0);
                }
#pragma unroll
                for (int r = 0; r < 4; r++) a[r] *= 8.0f;   // att / SCALE, SCALE=1/8
                av[fn] = a;
                // Gumbel/lgamma chain — independent of the MFMAs above, fills
                // their latency; spill G (fp16) in fragment layout.
                int k = kt * 64 + fn * 16 + lr;
                hf4 gh;
#pragma unroll
                for (int r = 0; r < 4; r++) {
                    float u  = Up[(size_t)r * 512 + k];
                    float tt = (1.0f - u) + 1e-20f;
                    float gl = 1e-20f - __logf(tt);
                    float g  = __logf(gl);
                    gh[r] = (hf_t)lgamma_fast(fmaf(2.0f, g, 3.0f)); // 1+1/k+(1/k)*gumbel
                }
                *(hf4*)(GSp + ((size_t)(kt*4 + fn) * 64 + lane) * 4) = gh;
            }
#pragma unroll
            for (int r = 0; r < 4; r++) {
                float mx = fmaxf(fmaxf(av[0][r], av[1][r]), fmaxf(av[2][r], av[3][r]));
                mx = fmaxf(mx, __shfl_xor(mx, 1));
                mx = fmaxf(mx, __shfl_xor(mx, 2));
                mx = fmaxf(mx, __shfl_xor(mx, 4));
                mx = fmaxf(mx, __shfl_xor(mx, 8));
                float nm = fmaxf(M1[r], mx);
                float es = __expf(av[0][r]-nm) + __expf(av[1][r]-nm)
                         + __expf(av[2][r]-nm) + __expf(av[3][r]-nm);
                es += __shfl_xor(es, 1); es += __shfl_xor(es, 2);
                es += __shfl_xor(es, 4); es += __shfl_xor(es, 8);
                Z1[r] = Z1[r] * __expf(M1[r] - nm) + es;
                M1[r] = nm;
            }
        }
#pragma unroll
        for (int r = 0; r < 4; r++) C[r] = M1[r] + logf(Z1[r]);
    }

    // ---- pass B: restage K+V; recompute s; lp + spilled G; softmax-2 + PV --
    float M2[4], Z2[4];
    f32x4 oacc[4] = {};
#pragma unroll
    for (int r = 0; r < 4; r++) { M2[r] = -INFINITY; Z2[r] = 0.f; }
    float S1f = 0.f;

    for (int kt = 0; kt < 8; kt++) {
        __syncthreads();
        {   // stage K hi/lo + V^T tile (all vectorized) + alpha tile
            size_t src = ((size_t)(b*512 + kt*64 + sr)) * 1024 + h*64 + sj;
            *(bh8*)&KtH[sr][sj] = *(const bh8*)(KH + src);
            *(bh8*)&KtL[sr][sj] = *(const bh8*)(KL + src);
            const bh_t* vsrc = VT + ((size_t)bh * 64 + sr) * 512 + kt*64 + sj;
            *(bh8*)&Vt[sr][sj] = *(const bh8*)vsrc;
            if (t < 64) Asm[t] = AL[(size_t)bh * 512 + kt * 64 + t];
        }
        __syncthreads();
        f32x4 wv[4];
#pragma unroll
        for (int fn = 0; fn < 4; fn++) {
            f32x4 a = {};
#pragma unroll
            for (int ks = 0; ks < 2; ks++) {
                bh8 kb  = *(bh8*)&KtH[fn*16 + lr][ks*32 + kg*8];
                bh8 kl2 = *(bh8*)&KtL[fn*16 + lr][ks*32 + kg*8];
                a = MFMA_BF16(qh[ks], kb,  a, 0, 0, 0);
                a = MFMA_BF16(qh[ks], kl2, a, 0, 0, 0);
                a = MFMA_BF16(ql[ks], kb,  a, 0, 0, 0);
            }
            hf4 gh = *(const hf4*)(GSp + ((size_t)(kt*4 + fn) * 64 + lane) * 4);
            float alv = Asm[fn * 16 + lr];
#pragma unroll
            for (int r = 0; r < 4; r++) {
                float s  = fmaf(a[r], 8.0f, -C[r]);      // logit - (M1+lnZ1)
                float ex = __expf(s);                     // = softmax-1 prob
                float lp = __logf(ex + 1e-20f);           // exact EPS-floor
                wv[fn][r] = lp - (float)gh[r];
                S1f = fmaf(alv, lp, S1f);
            }
        }
#pragma unroll
        for (int r = 0; r < 4; r++) {
            float mx = fmaxf(fmaxf(wv[0][r], wv[1][r]), fmaxf(wv[2][r], wv[3][r]));
            mx = fmaxf(mx, __shfl_xor(mx, 1));
            mx = fmaxf(mx, __shfl_xor(mx, 2));
            mx = fmaxf(mx, __shfl_xor(mx, 4));
            mx = fmaxf(mx, __shfl_xor(mx, 8));
            float nm = fmaxf(M2[r], mx);
            float sc = __expf(M2[r] - nm);               // exp(-inf)=0, exp(0)=1
            float zs = 0.f;
#pragma unroll
            for (int fn = 0; fn < 4; fn++) {
                float sv = __expf(wv[fn][r] - nm);
                zs += sv;
                Sl[w][kg * 4 + r][fn * 16 + lr] = (bh_t)sv;
            }
            zs += __shfl_xor(zs, 1); zs += __shfl_xor(zs, 2);
            zs += __shfl_xor(zs, 4); zs += __shfl_xor(zs, 8);
            Z2[r] = fmaf(Z2[r], sc, zs);
            M2[r] = nm;
#pragma unroll
            for (int fo = 0; fo < 4; fo++) oacc[fo][r] *= sc;
        }
        // no extra barrier: Sl slice is per-wave (program-ordered); Vt/KtH
        // staged behind barrier and only rewritten after next loop-top barrier.
        bh8 sa0 = *(bh8*)&Sl[w][lr][kg*8];
        bh8 sa1 = *(bh8*)&Sl[w][lr][32 + kg*8];
#pragma unroll
        for (int fo = 0; fo < 4; fo++) {
            bh8 v0 = *(bh8*)&Vt[fo*16 + lr][kg*8];
            bh8 v1 = *(bh8*)&Vt[fo*16 + lr][32 + kg*8];
            oacc[fo] = MFMA_BF16(sa0, v0, oacc[fo], 0, 0, 0);
            oacc[fo] = MFMA_BF16(sa1, v1, oacc[fo], 0, 0, 0);
        }
    }
    float rz[4];
#pragma unroll
    for (int r = 0; r < 4; r++) rz[r] = 1.0f / Z2[r];
    // head output (bf16): HO[b, q, h*64+dv]
#pragma unroll
    for (int fo = 0; fo < 4; fo++) {
#pragma unroll
        for (int r = 0; r < 4; r++) {
            int q = q0 + kg * 4 + r;
            int dv = fo * 16 + lr;
            HOB[((size_t)(b * 512 + q)) * 1024 + h * 64 + dv] = (bh_t)(oacc[fo][r] * rz[r]);
        }
    }
    red[t] = S1f; __syncthreads();
    for (int s = 256; s > 0; s >>= 1) { if (t < s) red[t] += red[t+s]; __syncthreads(); }
    if (t == 0) atomicAdd(&acc[0], (double)red[0]);
}

__global__ void k_kl(const double* __restrict__ acc, float* __restrict__ out)
{
    if (threadIdx.x == 0 && blockIdx.x == 0) {
        // S2 = sum(exp(log(softmax+1e-20))) = B*H*L (+ BHL*L*1e-20, negligible)
        double kl = (-acc[0] + 512.0 * acc[2] + 65536.0) / 33554432.0;
        out[4194304] = (float)kl;
    }
}

// ---------------------------------------------------------------------------
extern "C" void kernel_launch(void* const* d_in, const int* in_sizes, int n_in,
                              void* d_out, int out_size, void* d_ws, size_t ws_size,
                              hipStream_t stream)
{
    (void)in_sizes; (void)n_in; (void)d_ws; (void)ws_size; (void)out_size;
    const float* queries = (const float*)d_in[0];
    const float* keys    = (const float*)d_in[1];
    const float* values  = (const float*)d_in[2];
    const float* unif    = (const float*)d_in[3];
    const float* Wq = (const float*)d_in[4];  const float* bq = (const float*)d_in[5];
    const float* Wk = (const float*)d_in[6];  const float* bk = (const float*)d_in[7];
    const float* Wv = (const float*)d_in[8];  const float* bv = (const float*)d_in[9];
    const float* Wo = (const float*)d_in[10]; const float* bo = (const float*)d_in[11];
    const float* Wp1 = (const float*)d_in[12]; const float* bp1 = (const float*)d_in[13];
    const float* Wp2 = (const float*)d_in[14]; const float* bp2 = (const float*)d_in[15];

    unsigned char* ws = nullptr;
    hipGetSymbolAddress((void**)&ws, HIP_SYMBOL(g_ws));

    bh_t* QHI = (bh_t*)(ws + O_QHI); bh_t* QLO = (bh_t*)(ws + O_QLO);
    bh_t* KHI = (bh_t*)(ws + O_KHI); bh_t* KLO = (bh_t*)(ws + O_KLO);
    bh_t* VTp = (bh_t*)(ws + O_VT);
    bh_t* WQH = (bh_t*)(ws + O_WQH); bh_t* WQL = (bh_t*)(ws + O_WQL);
    bh_t* WKH = (bh_t*)(ws + O_WKH); bh_t* WKL = (bh_t*)(ws + O_WKL);
    bh_t* WVH = (bh_t*)(ws + O_WVH); bh_t* WVL = (bh_t*)(ws + O_WVL);
    bh_t* WOH = (bh_t*)(ws + O_WOH); bh_t* WOL = (bh_t*)(ws + O_WOL);
    bh_t* WP1H = (bh_t*)(ws + O_WP1H); bh_t* WP1L = (bh_t*)(ws + O_WP1L);
    float* DG    = (float*)(ws + O_DG);
    float* ALPHA = (float*)(ws + O_ALPHA);
    bh_t*  HOB   = (bh_t*)(ws + O_HO);
    hf_t*  GS    = (hf_t*)(ws + O_GS);
    double* ACC  = (double*)(ws + O_ACC);
    float* outF  = (float*)d_out;

    k_zero<<<1, 64, 0, stream>>>(ACC);

    // all four 1024^2 weight transposes in one launch (dst planes contiguous)
    k_transpose_split4<<<dim3(16,16,4), 256, 0, stream>>>(Wq, Wk, Wv, Wo, WQH);
    k_transpose_split<<<dim3(16,1), 256, 0, stream>>>(Wp1, WP1H, WP1L, 64, 1024);

    k_gemm<true, 0,false><<<dim3(16,64), 256, 0, stream>>>(queries, nullptr, WQH, WQL, bq, QHI, QLO, nullptr);
    k_gemm<true, 0,false><<<dim3(16,64), 256, 0, stream>>>(keys,    nullptr, WKH, WKL, bk, KHI, KLO, nullptr);
    k_gemm<false,3,false><<<dim3(16,64), 256, 0, stream>>>(values,  nullptr, WVH, WVL, bv, VTp, nullptr, nullptr);

    k_prior<<<dim3(8,16,8), 256, 0, stream>>>(KHI, WP1H, bp1, Wp2, bp2, DG);
    k_alpha<<<128, 512, 0, stream>>>(DG, ALPHA, ACC);

    k_attn<<<512, 512, 0, stream>>>(QHI, QLO, KHI, KLO, VTp, unif, ALPHA, HOB, GS, ACC);

    k_gemm<false,2,true><<<dim3(16,64), 256, 0, stream>>>(nullptr, HOB, WOH, WOL, bo, nullptr, nullptr, outF);
    k_kl<<<1, 1, 0, stream>>>(ACC, outF);
}

// Round 11
// 358.786 us; speedup vs baseline: 1.4115x; 1.0107x over previous
//
#include <hip/hip_runtime.h>
#include <math.h>

// ---------------------------------------------------------------------------
// BayesianAttention (B=8, L=512, D=1024, H=16, DK=DV=64, k_weibull=0.5)
// Numerics plan:
//   - Q/K projections + QK^T: split-bf16 (hi/lo) 3-MFMA => ~fp32-ish precision
//   - V projection, prior MLP, PV, output GEMM: plain bf16 MFMA
//   - k_attn (R10, proven 193us): QBLK=128, fp16 G-spill:
//       pass A: QK MFMA + online (M1,Z1) + Gumbel/lgamma G chain interleaved
//       pass B: K-restage + 3-MFMA logit recompute + exp/log + softmax-2 + PV
//   - k_gemm (R11): 128x64 tile, 4 waves, 4x2 frags/wave -> 24 MFMA : 12
//     ds_read per K-step (was 12:12); Q+K projections fused in one z=2 launch
//     (1024 co-resident blocks = 4/CU for barrier-drain overlap).
//   - EPS-floor lp = log(exp(s-C)+1e-20) kept exact (load-bearing tail)
//   - S2 = sum exp(log(softmax+1e-20)) = B*H*L exactly -> constant in k_kl
//   - KL: kl_mean = (-S1 + L*T2 + S2) / (B*H*L*L)
// ---------------------------------------------------------------------------

typedef __bf16 bh_t;
typedef bh_t  bh8  __attribute__((ext_vector_type(8)));
typedef float f32x4 __attribute__((ext_vector_type(4)));
typedef _Float16 hf_t;
typedef hf_t  hf4  __attribute__((ext_vector_type(4)));

#define MFMA_BF16 __builtin_amdgcn_mfma_f32_16x16x32_bf16

// ---- scratch layout in a device-global arena (no dependence on ws_size) ----
static constexpr size_t P2 = 4096ull*1024ull*2ull;   // bf16 [4096][1024] plane
static constexpr size_t W2 = 1024ull*1024ull*2ull;   // bf16 [1024][1024] plane
static constexpr size_t O_QHI = 0;                   // Q hi/lo, K hi/lo contiguous
static constexpr size_t O_QLO = O_QHI + P2;
static constexpr size_t O_KHI = O_QLO + P2;
static constexpr size_t O_KLO = O_KHI + P2;
static constexpr size_t O_VT  = O_KLO + P2;          // bf16 [128][64][512] V^T
static constexpr size_t O_WQH = O_VT  + P2;          // 4x {hi,lo} contiguous
static constexpr size_t O_WQL = O_WQH + W2;
static constexpr size_t O_WKH = O_WQL + W2;
static constexpr size_t O_WKL = O_WKH + W2;
static constexpr size_t O_WVH = O_WKL + W2;
static constexpr size_t O_WVL = O_WVH + W2;
static constexpr size_t O_WOH = O_WVL + W2;
static constexpr size_t O_WOL = O_WOH + W2;
static constexpr size_t O_WP1H = O_WOL + W2;
static constexpr size_t O_WP1L = O_WP1H + 1024ull*64ull*2ull;
static constexpr size_t O_DG   = O_WP1L + 1024ull*64ull*2ull;
static constexpr size_t O_ALPHA= O_DG + 65536ull*4ull;
static constexpr size_t O_HO   = O_ALPHA + 65536ull*4ull;               // bf16 [4096][1024]
static constexpr size_t O_GS   = O_HO + P2;                             // fp16 G spill, 64 MB
static constexpr size_t O_ACC  = O_GS + 512ull*65536ull*2ull;           // 3 doubles
static constexpr size_t WS_TOTAL = O_ACC + 256;

__device__ __align__(256) unsigned char g_ws[WS_TOTAL];

// ---------------------------------------------------------------------------
// slim lgamma: reflection + shift-to-(>=4) + 2-term Stirling, all hw trans.
// abs err ~1e-5 away from poles; poles only where weight -> 0 / ref is inf too.
__device__ __forceinline__ float lgamma_fast(float x)
{
    float ax = (x < 0.5f) ? (1.0f - x) : x;          // ax >= 0.5
    float p  = ax*(ax+1.f)*(ax+2.f)*(ax+3.f);
    bool  sm = ax < 4.0f;
    float lsh = sm ? __logf(p) : 0.0f;
    float y   = sm ? (ax + 4.0f) : ax;               // y >= 4
    float ly  = __logf(y);
    float inv = __builtin_amdgcn_rcpf(y);
    float i2  = inv * inv;
    float stir = fmaf(y - 0.5f, ly, -y) + 0.91893853320467274f
               + inv * fmaf(-2.7777777777e-3f, i2, 8.3333333333e-2f);
    float core = stir - lsh;                         // lgamma(ax)
    // reflection: lgamma(x) = ln(pi) - ln|sin(pi x)| - lgamma(1-x)
    float r  = x - rintf(x);                         // |r| <= 0.5
    float sp = __sinf(3.14159265358979f * r);
    float rres = 1.14472988584940017f - __logf(fabsf(sp)) - core;
    return (x < 0.5f) ? rres : core;
}

// ---------------------------------------------------------------------------
__global__ void k_zero(double* a)
{
    if (threadIdx.x < 4) a[threadIdx.x] = 0.0;
}

// transpose f32 [rows][cols] -> bf16 hi/lo [cols][rows] (single matrix)
__global__ __launch_bounds__(256) void k_transpose_split(
    const float* __restrict__ in, bh_t* __restrict__ oh, bh_t* __restrict__ ol,
    int rows, int cols)
{
    __shared__ float tile[64][65];
    const int bc = blockIdx.x * 64, br = blockIdx.y * 64;
    const int t = threadIdx.x;
    const int r = t >> 2, c0 = (t & 3) * 16;
#pragma unroll
    for (int i = 0; i < 16; i += 4) {
        float4 v = *(const float4*)(in + (size_t)(br + r) * cols + bc + c0 + i);
        tile[r][c0+i]   = v.x; tile[r][c0+i+1] = v.y;
        tile[r][c0+i+2] = v.z; tile[r][c0+i+3] = v.w;
    }
    __syncthreads();
    bh8 hv[2], lv[2];
#pragma unroll
    for (int i = 0; i < 16; i++) {
        float x = tile[c0 + i][r];
        bh_t hh = (bh_t)x;
        hv[i >> 3][i & 7] = hh;
        lv[i >> 3][i & 7] = (bh_t)(x - (float)hh);
    }
    size_t ob = (size_t)(bc + r) * rows + br + c0;
    *(bh8*)(oh + ob)     = hv[0];
    *(bh8*)(oh + ob + 8) = hv[1];
    *(bh8*)(ol + ob)     = lv[0];
    *(bh8*)(ol + ob + 8) = lv[1];
}

// fused: transpose+split all four 1024x1024 weights (z selects matrix);
// dst planes are contiguous in the arena: [z][hi|lo] each 1024*1024 bf16.
__global__ __launch_bounds__(256) void k_transpose_split4(
    const float* __restrict__ W0, const float* __restrict__ W1,
    const float* __restrict__ W2_, const float* __restrict__ W3,
    bh_t* __restrict__ OH)
{
    __shared__ float tile[64][65];
    const int z = blockIdx.z;
    const float* in = (z == 0) ? W0 : (z == 1) ? W1 : (z == 2) ? W2_ : W3;
    bh_t* oh = OH + (size_t)z * 2ull * 1024ull * 1024ull;
    bh_t* ol = oh + 1024ull * 1024ull;
    const int bc = blockIdx.x * 64, br = blockIdx.y * 64;
    const int t = threadIdx.x;
    const int r = t >> 2, c0 = (t & 3) * 16;
#pragma unroll
    for (int i = 0; i < 16; i += 4) {
        float4 v = *(const float4*)(in + (size_t)(br + r) * 1024 + bc + c0 + i);
        tile[r][c0+i]   = v.x; tile[r][c0+i+1] = v.y;
        tile[r][c0+i+2] = v.z; tile[r][c0+i+3] = v.w;
    }
    __syncthreads();
    bh8 hv[2], lv[2];
#pragma unroll
    for (int i = 0; i < 16; i++) {
        float x = tile[c0 + i][r];
        bh_t hh = (bh_t)x;
        hv[i >> 3][i & 7] = hh;
        lv[i >> 3][i & 7] = (bh_t)(x - (float)hh);
    }
    size_t ob = (size_t)(bc + r) * 1024 + br + c0;
    *(bh8*)(oh + ob)     = hv[0];
    *(bh8*)(oh + ob + 8) = hv[1];
    *(bh8*)(ol + ob)     = lv[0];
    *(bh8*)(ol + ob + 8) = lv[1];
}

// ---------------------------------------------------------------------------
// GEMM body: C[128x64 tile] = A[4096][1024] @ W^T + bias, K=1024, BK=32.
// 4 waves, per-wave 64x32 = 4x2 frags -> 24 MFMA : 12 ds_read per K-step
// (split) vs 12:12 of the old 64x64 tile.
// OMODE 0: bf16 hi+lo planes; 1: bf16 plane; 2: f32; 3: bf16 into VT layout.
template<bool SPLIT, int OMODE, bool ABF>
__device__ __forceinline__ void gemm_body(
    const float* __restrict__ A, const bh_t* __restrict__ ABH,
    const bh_t* __restrict__ WH, const bh_t* __restrict__ WL,
    const float* __restrict__ bias,
    bh_t* __restrict__ oh, bh_t* __restrict__ ol, float* __restrict__ of,
    int n0, int m0)
{
    __shared__ __align__(16) bh_t Ah[128][40];
    __shared__ __align__(16) bh_t Al[128][40];
    __shared__ __align__(16) bh_t Bh[64][40];
    __shared__ __align__(16) bh_t Bl[64][40];
    const int t = threadIdx.x;
    const int lane = t & 63, w = t >> 6;
    const int lr = lane & 15, kg = lane >> 4;
    const int wm = (w & 1) * 64, wn = (w >> 1) * 32;
    const int ar = t >> 2, ac = (t & 3) * 8;
    f32x4 acc[4][2] = {};

    for (int kt = 0; kt < 1024; kt += 32) {
        __syncthreads();
        {
            if constexpr (ABF) {
                *(bh8*)&Ah[ar][ac]      = *(const bh8*)(ABH + (size_t)(m0 + ar) * 1024 + kt + ac);
                *(bh8*)&Ah[ar + 64][ac] = *(const bh8*)(ABH + (size_t)(m0 + ar + 64) * 1024 + kt + ac);
            } else {
#pragma unroll
                for (int half = 0; half < 2; half++) {
                    const float* ap = A + (size_t)(m0 + ar + half*64) * 1024 + kt + ac;
                    float4 v0 = *(const float4*)ap;
                    float4 v1 = *(const float4*)(ap + 4);
                    float xs[8] = {v0.x, v0.y, v0.z, v0.w, v1.x, v1.y, v1.z, v1.w};
                    bh8 h, l;
#pragma unroll
                    for (int i = 0; i < 8; i++) {
                        bh_t hh = (bh_t)xs[i];
                        h[i] = hh;
                        l[i] = (bh_t)(xs[i] - (float)hh);
                    }
                    *(bh8*)&Ah[ar + half*64][ac] = h;
                    if constexpr (SPLIT) *(bh8*)&Al[ar + half*64][ac] = l;
                }
            }
            size_t wb = (size_t)(n0 + ar) * 1024 + kt + ac;
            *(bh8*)&Bh[ar][ac] = *(const bh8*)(WH + wb);
            if constexpr (SPLIT) *(bh8*)&Bl[ar][ac] = *(const bh8*)(WL + wb);
        }
        __syncthreads();
#pragma unroll
        for (int fm = 0; fm < 4; fm++) {
            bh8 a_h = *(bh8*)&Ah[wm + fm*16 + lr][kg * 8];
            bh8 a_l;
            if constexpr (SPLIT) a_l = *(bh8*)&Al[wm + fm*16 + lr][kg * 8];
#pragma unroll
            for (int fn = 0; fn < 2; fn++) {
                bh8 b_h = *(bh8*)&Bh[wn + fn*16 + lr][kg * 8];
                acc[fm][fn] = MFMA_BF16(a_h, b_h, acc[fm][fn], 0, 0, 0);
                if constexpr (SPLIT) {
                    bh8 b_l = *(bh8*)&Bl[wn + fn*16 + lr][kg * 8];
                    acc[fm][fn] = MFMA_BF16(a_h, b_l, acc[fm][fn], 0, 0, 0);
                    acc[fm][fn] = MFMA_BF16(a_l, b_h, acc[fm][fn], 0, 0, 0);
                }
            }
        }
    }
#pragma unroll
    for (int fm = 0; fm < 4; fm++)
#pragma unroll
    for (int fn = 0; fn < 2; fn++) {
        int col = n0 + wn + fn*16 + lr;
        float bv = bias[col];
#pragma unroll
        for (int r = 0; r < 4; r++) {
            int row = m0 + wm + fm*16 + kg*4 + r;
            float c = acc[fm][fn][r] + bv;
            size_t idx = (size_t)row * 1024 + col;
            if constexpr (OMODE == 0) {
                bh_t hh = (bh_t)c;
                oh[idx] = hh;
                ol[idx] = (bh_t)(c - (float)hh);
            } else if constexpr (OMODE == 1) {
                oh[idx] = (bh_t)c;
            } else if constexpr (OMODE == 2) {
                of[idx] = c;
            } else {
                // VT layout: [(b*16+h)*64+dv][l], h=col>>6, dv=col&63
                int bb = row >> 9, ll = row & 511;
                oh[(((size_t)(bb*16 + (col >> 6)) * 64) + (col & 63)) * 512 + ll] = (bh_t)c;
            }
        }
    }
}

template<bool SPLIT, int OMODE, bool ABF>
__global__ __launch_bounds__(256) void k_gemm(
    const float* __restrict__ A, const bh_t* __restrict__ ABH,
    const bh_t* __restrict__ WH, const bh_t* __restrict__ WL,
    const float* __restrict__ bias,
    bh_t* __restrict__ oh, bh_t* __restrict__ ol, float* __restrict__ of)
{
    gemm_body<SPLIT, OMODE, ABF>(A, ABH, WH, WL, bias, oh, ol, of,
                                 blockIdx.x * 64, blockIdx.y * 128);
}

// fused Q+K split projections: z selects {queries,Wq,bq -> Q planes} vs
// {keys,Wk,bk -> K planes}; W and output planes are contiguous in the arena.
__global__ __launch_bounds__(256) void k_gemm_qk(
    const float* __restrict__ Aq, const float* __restrict__ Ak,
    const bh_t* __restrict__ Wbase, const float* __restrict__ bq,
    const float* __restrict__ bk, bh_t* __restrict__ Obase)
{
    const int z = blockIdx.z;
    const float* A = z ? Ak : Aq;
    const bh_t* WH = Wbase + (size_t)z * 2ull * 1024ull * 1024ull;
    const bh_t* WL = WH + 1024ull * 1024ull;
    const float* bias = z ? bk : bq;
    bh_t* oh = Obase + (size_t)z * 2ull * 4096ull * 1024ull;
    bh_t* ol = oh + 4096ull * 1024ull;
    gemm_body<true, 0, false>(A, nullptr, WH, WL, bias, oh, ol, nullptr,
                              blockIdx.x * 64, blockIdx.y * 128);
}

// dot_gamma[b,h,l] = Wp2 . leakyrelu(K_head[b,h,l,:] @ Wp1 + bp1) + bp2
__global__ __launch_bounds__(256) void k_prior(
    const bh_t* __restrict__ KH, const bh_t* __restrict__ WP1T,
    const float* __restrict__ bp1, const float* __restrict__ wp2,
    const float* __restrict__ bp2, float* __restrict__ DG)
{
    __shared__ __align__(16) bh_t Kt[64][72];
    __shared__ __align__(16) bh_t Wt[64][72];
    const int lt = blockIdx.x, h = blockIdx.y, b = blockIdx.z;
    const int t = threadIdx.x, lane = t & 63, w = t >> 6;
    const int lr = lane & 15, kg = lane >> 4;
    {
        int r = t >> 2, j0 = (t & 3) * 16;
        const bh_t* src = KH + ((size_t)(b*512 + lt*64 + r)) * 1024 + h*64 + j0;
        *(bh8*)&Kt[r][j0]     = *(const bh8*)src;
        *(bh8*)&Kt[r][j0 + 8] = *(const bh8*)(src + 8);
    }
    __syncthreads();
    bh8 af0 = *(bh8*)&Kt[w*16 + lr][kg * 8];
    bh8 af1 = *(bh8*)&Kt[w*16 + lr][32 + kg * 8];
    float dgp[4] = {0.f, 0.f, 0.f, 0.f};
    for (int dt = 0; dt < 16; dt++) {
        __syncthreads();
        {
            int r = t >> 2, j0 = (t & 3) * 16;
            const bh_t* src = WP1T + (size_t)(dt*64 + r) * 64 + j0;
            *(bh8*)&Wt[r][j0]     = *(const bh8*)src;
            *(bh8*)&Wt[r][j0 + 8] = *(const bh8*)(src + 8);
        }
        __syncthreads();
#pragma unroll
        for (int fn = 0; fn < 4; fn++) {
            bh8 b0 = *(bh8*)&Wt[fn*16 + lr][kg * 8];
            bh8 b1 = *(bh8*)&Wt[fn*16 + lr][32 + kg * 8];
            f32x4 acc = {};
            acc = MFMA_BF16(af0, b0, acc, 0, 0, 0);
            acc = MFMA_BF16(af1, b1, acc, 0, 0, 0);
            int d = dt*64 + fn*16 + lr;
            float bpv = bp1[d], wvv = wp2[d];
#pragma unroll
            for (int r = 0; r < 4; r++) {
                float hv = acc[r] + bpv;
                hv = (hv >= 0.f) ? hv : 0.01f * hv;
                dgp[r] = fmaf(hv, wvv, dgp[r]);
            }
        }
    }
#pragma unroll
    for (int r = 0; r < 4; r++) {
        float v = dgp[r];
        v += __shfl_xor(v, 1); v += __shfl_xor(v, 2);
        v += __shfl_xor(v, 4); v += __shfl_xor(v, 8);
        dgp[r] = v;
    }
    if (lr == 0) {
        float b2 = bp2[0];
        int bh = b * 16 + h;
#pragma unroll
        for (int r = 0; r < 4; r++)
            DG[(size_t)bh*512 + lt*64 + w*16 + kg*4 + r] = dgp[r] + b2;
    }
}

// alpha = softmax_k(dot_gamma); accumulate alpha-only KL terms into acc[2]
__global__ __launch_bounds__(512) void k_alpha(
    const float* __restrict__ DG, float* __restrict__ AL, double* __restrict__ acc)
{
    __shared__ float red[512];
    const int bh = blockIdx.x, t = threadIdx.x;
    float v = DG[(size_t)bh * 512 + t];
    red[t] = v; __syncthreads();
    for (int s = 256; s > 0; s >>= 1) { if (t < s) red[t] = fmaxf(red[t], red[t+s]); __syncthreads(); }
    float m = red[0]; __syncthreads();
    float e = expf(v - m);
    red[t] = e; __syncthreads();
    for (int s = 256; s > 0; s >>= 1) { if (t < s) red[t] += red[t+s]; __syncthreads(); }
    float ssum = red[0]; __syncthreads();
    float a = e / ssum;                 // * BETA_GAMMA (=1)
    AL[(size_t)bh * 512 + t] = a;
    // lg1 + 2*eulergamma = 0.6931471805599453 + 1.1544313298030658
    float t2 = a * 1.8475785103630112f + lgammaf(a + 1e-20f);
    red[t] = t2; __syncthreads();
    for (int s = 256; s > 0; s >>= 1) { if (t < s) red[t] += red[t+s]; __syncthreads(); }
    if (t == 0) atomicAdd(&acc[2], (double)red[0]);
}

// fused stochastic attention: one block per (b,h, 128-row q-chunk), 8 waves.
// pass A: QK split-MFMA + online (M1,Z1) + G chain -> fp16 spill (interleaved)
// pass B: K-restage + 3-MFMA logit recompute + exp/log + softmax-2 + PV (Vt LDS)
__global__ __launch_bounds__(512, 3) void k_attn(
    const bh_t* __restrict__ QH, const bh_t* __restrict__ QL,
    const bh_t* __restrict__ KH, const bh_t* __restrict__ KL,
    const bh_t* __restrict__ VT, const float* __restrict__ U,
    const float* __restrict__ AL, bh_t* __restrict__ HOB,
    hf_t* __restrict__ GS, double* __restrict__ acc)
{
    __shared__ __align__(16) bh_t KtH[64][72];
    __shared__ __align__(16) bh_t KtL[64][72];
    __shared__ __align__(16) bh_t Vt[64][72];
    __shared__ __align__(16) bh_t Sl[8][16][72];
    __shared__ float Asm[64];
    __shared__ float red[512];

    const int flat = blockIdx.x;
    const int bh = flat & 127, qc = flat >> 7;   // 4 q-chunks of one bh share an XCD
    const int b = bh >> 4, h = bh & 15;
    const int t = threadIdx.x, w = t >> 6, lane = t & 63;
    const int lr = lane & 15, kg = lane >> 4;
    const int q0 = qc * 128 + w * 16;
    const int sr = t >> 3, sj = (t & 7) * 8;
    const float* Up = U + ((size_t)bh * 512 + q0 + kg * 4) * 512;
    hf_t* GSp = GS + (size_t)flat * 65536 + (size_t)w * 8192;

    bh8 qh[2], ql[2];
    {
        size_t qb = ((size_t)(b * 512) + q0 + lr) * 1024 + h * 64;
        qh[0] = *(const bh8*)(QH + qb + kg * 8);
        qh[1] = *(const bh8*)(QH + qb + 32 + kg * 8);
        ql[0] = *(const bh8*)(QL + qb + kg * 8);
        ql[1] = *(const bh8*)(QL + qb + 32 + kg * 8);
    }
    float C[4];   // per-q-row M1 + lnZ1, carried A -> B

    // ---- pass A: logits (split-bf16 MFMA), G chain + fp16 spill, M1/Z1 ----
    {
        float M1[4], Z1[4];
#pragma unroll
        for (int r = 0; r < 4; r++) { M1[r] = -INFINITY; Z1[r] = 0.f; }

        for (int kt = 0; kt < 8; kt++) {
            __syncthreads();
            {
                size_t src = ((size_t)(b*512 + kt*64 + sr)) * 1024 + h*64 + sj;
                *(bh8*)&KtH[sr][sj] = *(const bh8*)(KH + src);
                *(bh8*)&KtL[sr][sj] = *(const bh8*)(KL + src);
            }
            __syncthreads();
            f32x4 av[4];
#pragma unroll
            for (int fn = 0; fn < 4; fn++) {
                f32x4 a = {};
#pragma unroll
                for (int ks = 0; ks < 2; ks++) {
                    bh8 kb  = *(bh8*)&KtH[fn*16 + lr][ks*32 + kg*8];
                    bh8 kl2 = *(bh8*)&KtL[fn*16 + lr][ks*32 + kg*8];
                    a = MFMA_BF16(qh[ks], kb,  a, 0, 0, 0);
                    a = MFMA_BF16(qh[ks], kl2, a, 0, 0, 0);
                    a = MFMA_BF16(ql[ks], kb,  a, 0, 0, 0);
                }
#pragma unroll
                for (int r = 0; r < 4; r++) a[r] *= 8.0f;   // att / SCALE, SCALE=1/8
                av[fn] = a;
                // Gumbel/lgamma chain — independent of the MFMAs above, fills
                // their latency; spill G (fp16) in fragment layout.
                int k = kt * 64 + fn * 16 + lr;
                hf4 gh;
#pragma unroll
                for (int r = 0; r < 4; r++) {
                    float u  = Up[(size_t)r * 512 + k];
                    float tt = (1.0f - u) + 1e-20f;
                    float gl = 1e-20f - __logf(tt);
                    float g  = __logf(gl);
                    gh[r] = (hf_t)lgamma_fast(fmaf(2.0f, g, 3.0f)); // 1+1/k+(1/k)*gumbel
                }
                *(hf4*)(GSp + ((size_t)(kt*4 + fn) * 64 + lane) * 4) = gh;
            }
#pragma unroll
            for (int r = 0; r < 4; r++) {
                float mx = fmaxf(fmaxf(av[0][r], av[1][r]), fmaxf(av[2][r], av[3][r]));
                mx = fmaxf(mx, __shfl_xor(mx, 1));
                mx = fmaxf(mx, __shfl_xor(mx, 2));
                mx = fmaxf(mx, __shfl_xor(mx, 4));
                mx = fmaxf(mx, __shfl_xor(mx, 8));
                float nm = fmaxf(M1[r], mx);
                float es = __expf(av[0][r]-nm) + __expf(av[1][r]-nm)
                         + __expf(av[2][r]-nm) + __expf(av[3][r]-nm);
                es += __shfl_xor(es, 1); es += __shfl_xor(es, 2);
                es += __shfl_xor(es, 4); es += __shfl_xor(es, 8);
                Z1[r] = Z1[r] * __expf(M1[r] - nm) + es;
                M1[r] = nm;
            }
        }
#pragma unroll
        for (int r = 0; r < 4; r++) C[r] = M1[r] + logf(Z1[r]);
    }

    // ---- pass B: restage K+V; recompute s; lp + spilled G; softmax-2 + PV --
    float M2[4], Z2[4];
    f32x4 oacc[4] = {};
#pragma unroll
    for (int r = 0; r < 4; r++) { M2[r] = -INFINITY; Z2[r] = 0.f; }
    float S1f = 0.f;

    for (int kt = 0; kt < 8; kt++) {
        __syncthreads();
        {   // stage K hi/lo + V^T tile (all vectorized) + alpha tile
            size_t src = ((size_t)(b*512 + kt*64 + sr)) * 1024 + h*64 + sj;
            *(bh8*)&KtH[sr][sj] = *(const bh8*)(KH + src);
            *(bh8*)&KtL[sr][sj] = *(const bh8*)(KL + src);
            const bh_t* vsrc = VT + ((size_t)bh * 64 + sr) * 512 + kt*64 + sj;
            *(bh8*)&Vt[sr][sj] = *(const bh8*)vsrc;
            if (t < 64) Asm[t] = AL[(size_t)bh * 512 + kt * 64 + t];
        }
        __syncthreads();
        f32x4 wv[4];
#pragma unroll
        for (int fn = 0; fn < 4; fn++) {
            f32x4 a = {};
#pragma unroll
            for (int ks = 0; ks < 2; ks++) {
                bh8 kb  = *(bh8*)&KtH[fn*16 + lr][ks*32 + kg*8];
                bh8 kl2 = *(bh8*)&KtL[fn*16 + lr][ks*32 + kg*8];
                a = MFMA_BF16(qh[ks], kb,  a, 0, 0, 0);
                a = MFMA_BF16(qh[ks], kl2, a, 0, 0, 0);
                a = MFMA_BF16(ql[ks], kb,  a, 0, 0, 0);
            }
            hf4 gh = *(const hf4*)(GSp + ((size_t)(kt*4 + fn) * 64 + lane) * 4);
            float alv = Asm[fn * 16 + lr];
#pragma unroll
            for (int r = 0; r < 4; r++) {
                float s  = fmaf(a[r], 8.0f, -C[r]);      // logit - (M1+lnZ1)
                float ex = __expf(s);                     // = softmax-1 prob
                float lp = __logf(ex + 1e-20f);           // exact EPS-floor
                wv[fn][r] = lp - (float)gh[r];
                S1f = fmaf(alv, lp, S1f);
            }
        }
#pragma unroll
        for (int r = 0; r < 4; r++) {
            float mx = fmaxf(fmaxf(wv[0][r], wv[1][r]), fmaxf(wv[2][r], wv[3][r]));
            mx = fmaxf(mx, __shfl_xor(mx, 1));
            mx = fmaxf(mx, __shfl_xor(mx, 2));
            mx = fmaxf(mx, __shfl_xor(mx, 4));
            mx = fmaxf(mx, __shfl_xor(mx, 8));
            float nm = fmaxf(M2[r], mx);
            float sc = __expf(M2[r] - nm);               // exp(-inf)=0, exp(0)=1
            float zs = 0.f;
#pragma unroll
            for (int fn = 0; fn < 4; fn++) {
                float sv = __expf(wv[fn][r] - nm);
                zs += sv;
                Sl[w][kg * 4 + r][fn * 16 + lr] = (bh_t)sv;
            }
            zs += __shfl_xor(zs, 1); zs += __shfl_xor(zs, 2);
            zs += __shfl_xor(zs, 4); zs += __shfl_xor(zs, 8);
            Z2[r] = fmaf(Z2[r], sc, zs);
            M2[r] = nm;
#pragma unroll
            for (int fo = 0; fo < 4; fo++) oacc[fo][r] *= sc;
        }
        // no extra barrier: Sl slice is per-wave (program-ordered); Vt/KtH
        // staged behind barrier and only rewritten after next loop-top barrier.
        bh8 sa0 = *(bh8*)&Sl[w][lr][kg*8];
        bh8 sa1 = *(bh8*)&Sl[w][lr][32 + kg*8];
#pragma unroll
        for (int fo = 0; fo < 4; fo++) {
            bh8 v0 = *(bh8*)&Vt[fo*16 + lr][kg*8];
            bh8 v1 = *(bh8*)&Vt[fo*16 + lr][32 + kg*8];
            oacc[fo] = MFMA_BF16(sa0, v0, oacc[fo], 0, 0, 0);
            oacc[fo] = MFMA_BF16(sa1, v1, oacc[fo], 0, 0, 0);
        }
    }
    float rz[4];
#pragma unroll
    for (int r = 0; r < 4; r++) rz[r] = 1.0f / Z2[r];
    // head output (bf16): HO[b, q, h*64+dv]
#pragma unroll
    for (int fo = 0; fo < 4; fo++) {
#pragma unroll
        for (int r = 0; r < 4; r++) {
            int q = q0 + kg * 4 + r;
            int dv = fo * 16 + lr;
            HOB[((size_t)(b * 512 + q)) * 1024 + h * 64 + dv] = (bh_t)(oacc[fo][r] * rz[r]);
        }
    }
    red[t] = S1f; __syncthreads();
    for (int s = 256; s > 0; s >>= 1) { if (t < s) red[t] += red[t+s]; __syncthreads(); }
    if (t == 0) atomicAdd(&acc[0], (double)red[0]);
}

__global__ void k_kl(const double* __restrict__ acc, float* __restrict__ out)
{
    if (threadIdx.x == 0 && blockIdx.x == 0) {
        // S2 = sum(exp(log(softmax+1e-20))) = B*H*L (+ BHL*L*1e-20, negligible)
        double kl = (-acc[0] + 512.0 * acc[2] + 65536.0) / 33554432.0;
        out[4194304] = (float)kl;
    }
}

// ---------------------------------------------------------------------------
extern "C" void kernel_launch(void* const* d_in, const int* in_sizes, int n_in,
                              void* d_out, int out_size, void* d_ws, size_t ws_size,
                              hipStream_t stream)
{
    (void)in_sizes; (void)n_in; (void)d_ws; (void)ws_size; (void)out_size;
    const float* queries = (const float*)d_in[0];
    const float* keys    = (const float*)d_in[1];
    const float* values  = (const float*)d_in[2];
    const float* unif    = (const float*)d_in[3];
    const float* Wq = (const float*)d_in[4];  const float* bq = (const float*)d_in[5];
    const float* Wk = (const float*)d_in[6];  const float* bk = (const float*)d_in[7];
    const float* Wv = (const float*)d_in[8];  const float* bv = (const float*)d_in[9];
    const float* Wo = (const float*)d_in[10]; const float* bo = (const float*)d_in[11];
    const float* Wp1 = (const float*)d_in[12]; const float* bp1 = (const float*)d_in[13];
    const float* Wp2 = (const float*)d_in[14]; const float* bp2 = (const float*)d_in[15];

    unsigned char* ws = nullptr;
    hipGetSymbolAddress((void**)&ws, HIP_SYMBOL(g_ws));

    bh_t* QHI = (bh_t*)(ws + O_QHI);
    bh_t* KHI = (bh_t*)(ws + O_KHI); bh_t* KLO = (bh_t*)(ws + O_KLO);
    bh_t* QLO = (bh_t*)(ws + O_QLO);
    bh_t* VTp = (bh_t*)(ws + O_VT);
    bh_t* WQH = (bh_t*)(ws + O_WQH);
    bh_t* WVH = (bh_t*)(ws + O_WVH); bh_t* WVL = (bh_t*)(ws + O_WVL);
    bh_t* WOH = (bh_t*)(ws + O_WOH); bh_t* WOL = (bh_t*)(ws + O_WOL);
    bh_t* WP1H = (bh_t*)(ws + O_WP1H); bh_t* WP1L = (bh_t*)(ws + O_WP1L);
    float* DG    = (float*)(ws + O_DG);
    float* ALPHA = (float*)(ws + O_ALPHA);
    bh_t*  HOB   = (bh_t*)(ws + O_HO);
    hf_t*  GS    = (hf_t*)(ws + O_GS);
    double* ACC  = (double*)(ws + O_ACC);
    float* outF  = (float*)d_out;

    k_zero<<<1, 64, 0, stream>>>(ACC);

    // all four 1024^2 weight transposes in one launch (dst planes contiguous)
    k_transpose_split4<<<dim3(16,16,4), 256, 0, stream>>>(Wq, Wk, Wv, Wo, WQH);
    k_transpose_split<<<dim3(16,1), 256, 0, stream>>>(Wp1, WP1H, WP1L, 64, 1024);

    // Q and K split projections fused (z=2): 1024 blocks co-resident
    k_gemm_qk<<<dim3(16,32,2), 256, 0, stream>>>(queries, keys, WQH, bq, bk, QHI);
    k_gemm<false,3,false><<<dim3(16,32), 256, 0, stream>>>(values, nullptr, WVH, WVL, bv, VTp, nullptr, nullptr);

    k_prior<<<dim3(8,16,8), 256, 0, stream>>>(KHI, WP1H, bp1, Wp2, bp2, DG);
    k_alpha<<<128, 512, 0, stream>>>(DG, ALPHA, ACC);

    k_attn<<<512, 512, 0, stream>>>(QHI, QLO, KHI, KLO, VTp, unif, ALPHA, HOB, GS, ACC);

    k_gemm<false,2,true><<<dim3(16,32), 256, 0, stream>>>(nullptr, HOB, WOH, WOL, bo, nullptr, nullptr, outF);
    k_kl<<<1, 1, 0, stream>>>(ACC, outF);
}

// Round 12
// 339.710 us; speedup vs baseline: 1.4908x; 1.0562x over previous
//
#include <hip/hip_runtime.h>
#include <math.h>

// ---------------------------------------------------------------------------
// BayesianAttention (B=8, L=512, D=1024, H=16, DK=DV=64, k_weibull=0.5)
// Numerics plan:
//   - Q/K projections + QK^T: split-bf16 (hi/lo) 3-MFMA => ~fp32-ish precision
//   - V projection, prior MLP, PV, output GEMM: plain bf16 MFMA
//   - k_attn (R10/R11, proven 193us): QBLK=128, fp16 G-spill:
//       pass A: QK MFMA + online (M1,Z1) + Gumbel/lgamma G chain interleaved
//       pass B: K-restage + 3-MFMA logit recompute + exp/log + softmax-2 + PV
//   - k_gemm (R12): A pre-split to bf16 planes ONCE (k_splitA) -> K-loop
//     staging is pure load/ds_write (no f32->bf16 cvt, was 16x redundant);
//     128x128 tile, 4 waves, 4x4 frags -> 48 MFMA : 16 ds_read (split).
//   - EPS-floor lp = log(exp(s-C)+1e-20) kept exact (load-bearing tail)
//   - S2 = sum exp(log(softmax+1e-20)) = B*H*L exactly -> constant (k_kl fold)
//   - KL: kl_mean = (-S1 + L*T2 + S2) / (B*H*L*L)
// ---------------------------------------------------------------------------

typedef __bf16 bh_t;
typedef bh_t  bh8  __attribute__((ext_vector_type(8)));
typedef float f32x4 __attribute__((ext_vector_type(4)));
typedef _Float16 hf_t;
typedef hf_t  hf4  __attribute__((ext_vector_type(4)));

#define MFMA_BF16 __builtin_amdgcn_mfma_f32_16x16x32_bf16

// ---- scratch layout in a device-global arena (no dependence on ws_size) ----
static constexpr size_t PE = 4096ull*1024ull;        // elements in a [4096][1024] plane
static constexpr size_t P2 = PE*2ull;                // bytes of a bf16 plane
static constexpr size_t W2 = 1024ull*1024ull*2ull;   // bf16 [1024][1024] plane
static constexpr size_t O_QHI = 0;                   // Q hi/lo, K hi/lo contiguous
static constexpr size_t O_QLO = O_QHI + P2;
static constexpr size_t O_KHI = O_QLO + P2;
static constexpr size_t O_KLO = O_KHI + P2;
static constexpr size_t O_VT  = O_KLO + P2;          // bf16 [128][64][512] V^T
static constexpr size_t O_WQH = O_VT  + P2;          // 4x {hi,lo} contiguous
static constexpr size_t O_WQL = O_WQH + W2;
static constexpr size_t O_WKH = O_WQL + W2;
static constexpr size_t O_WKL = O_WKH + W2;
static constexpr size_t O_WVH = O_WKL + W2;
static constexpr size_t O_WVL = O_WVH + W2;
static constexpr size_t O_WOH = O_WVL + W2;
static constexpr size_t O_WOL = O_WOH + W2;
static constexpr size_t O_WP1H = O_WOL + W2;
static constexpr size_t O_WP1L = O_WP1H + 1024ull*64ull*2ull;
static constexpr size_t O_DG   = O_WP1L + 1024ull*64ull*2ull;
static constexpr size_t O_ALPHA= O_DG + 65536ull*4ull;
static constexpr size_t O_HO   = O_ALPHA + 65536ull*4ull;               // bf16 [4096][1024]
static constexpr size_t O_GS   = O_HO + P2;                             // fp16 G spill, 64 MB
static constexpr size_t O_ACC  = O_GS + 512ull*65536ull*2ull;           // 3 doubles
static constexpr size_t O_AQH  = O_ACC + 256;        // pre-split A planes:
static constexpr size_t WS_TOTAL = O_AQH + 5ull*P2;  // AQH,AQL,AKH,AKL,AVH

__device__ __align__(256) unsigned char g_ws[WS_TOTAL];

// ---------------------------------------------------------------------------
// slim lgamma: reflection + shift-to-(>=4) + 2-term Stirling, all hw trans.
__device__ __forceinline__ float lgamma_fast(float x)
{
    float ax = (x < 0.5f) ? (1.0f - x) : x;          // ax >= 0.5
    float p  = ax*(ax+1.f)*(ax+2.f)*(ax+3.f);
    bool  sm = ax < 4.0f;
    float lsh = sm ? __logf(p) : 0.0f;
    float y   = sm ? (ax + 4.0f) : ax;               // y >= 4
    float ly  = __logf(y);
    float inv = __builtin_amdgcn_rcpf(y);
    float i2  = inv * inv;
    float stir = fmaf(y - 0.5f, ly, -y) + 0.91893853320467274f
               + inv * fmaf(-2.7777777777e-3f, i2, 8.3333333333e-2f);
    float core = stir - lsh;                         // lgamma(ax)
    float r  = x - rintf(x);                         // |r| <= 0.5
    float sp = __sinf(3.14159265358979f * r);
    float rres = 1.14472988584940017f - __logf(fabsf(sp)) - core;
    return (x < 0.5f) ? rres : core;
}

// ---------------------------------------------------------------------------
// transpose f32 [rows][cols] -> bf16 hi/lo [cols][rows] (single matrix)
__global__ __launch_bounds__(256) void k_transpose_split(
    const float* __restrict__ in, bh_t* __restrict__ oh, bh_t* __restrict__ ol,
    int rows, int cols)
{
    __shared__ float tile[64][65];
    const int bc = blockIdx.x * 64, br = blockIdx.y * 64;
    const int t = threadIdx.x;
    const int r = t >> 2, c0 = (t & 3) * 16;
#pragma unroll
    for (int i = 0; i < 16; i += 4) {
        float4 v = *(const float4*)(in + (size_t)(br + r) * cols + bc + c0 + i);
        tile[r][c0+i]   = v.x; tile[r][c0+i+1] = v.y;
        tile[r][c0+i+2] = v.z; tile[r][c0+i+3] = v.w;
    }
    __syncthreads();
    bh8 hv[2], lv[2];
#pragma unroll
    for (int i = 0; i < 16; i++) {
        float x = tile[c0 + i][r];
        bh_t hh = (bh_t)x;
        hv[i >> 3][i & 7] = hh;
        lv[i >> 3][i & 7] = (bh_t)(x - (float)hh);
    }
    size_t ob = (size_t)(bc + r) * rows + br + c0;
    *(bh8*)(oh + ob)     = hv[0];
    *(bh8*)(oh + ob + 8) = hv[1];
    *(bh8*)(ol + ob)     = lv[0];
    *(bh8*)(ol + ob + 8) = lv[1];
}

// fused: transpose+split all four 1024x1024 weights (z selects matrix);
// also zeroes the ACC doubles (block 0 of z==0).
__global__ __launch_bounds__(256) void k_transpose_split4(
    const float* __restrict__ W0, const float* __restrict__ W1,
    const float* __restrict__ W2_, const float* __restrict__ W3,
    bh_t* __restrict__ OH, double* __restrict__ acc)
{
    __shared__ float tile[64][65];
    const int z = blockIdx.z;
    if (z == 0 && blockIdx.x == 0 && blockIdx.y == 0 && threadIdx.x < 4)
        acc[threadIdx.x] = 0.0;
    const float* in = (z == 0) ? W0 : (z == 1) ? W1 : (z == 2) ? W2_ : W3;
    bh_t* oh = OH + (size_t)z * 2ull * 1024ull * 1024ull;
    bh_t* ol = oh + 1024ull * 1024ull;
    const int bc = blockIdx.x * 64, br = blockIdx.y * 64;
    const int t = threadIdx.x;
    const int r = t >> 2, c0 = (t & 3) * 16;
#pragma unroll
    for (int i = 0; i < 16; i += 4) {
        float4 v = *(const float4*)(in + (size_t)(br + r) * 1024 + bc + c0 + i);
        tile[r][c0+i]   = v.x; tile[r][c0+i+1] = v.y;
        tile[r][c0+i+2] = v.z; tile[r][c0+i+3] = v.w;
    }
    __syncthreads();
    bh8 hv[2], lv[2];
#pragma unroll
    for (int i = 0; i < 16; i++) {
        float x = tile[c0 + i][r];
        bh_t hh = (bh_t)x;
        hv[i >> 3][i & 7] = hh;
        lv[i >> 3][i & 7] = (bh_t)(x - (float)hh);
    }
    size_t ob = (size_t)(bc + r) * 1024 + br + c0;
    *(bh8*)(oh + ob)     = hv[0];
    *(bh8*)(oh + ob + 8) = hv[1];
    *(bh8*)(ol + ob)     = lv[0];
    *(bh8*)(ol + ob + 8) = lv[1];
}

// pre-split activations: z=0 queries -> AQH/AQL, z=1 keys -> AKH/AKL,
// z=2 values -> AVH (plain bf16). Row-major [4096][1024] planes.
__global__ __launch_bounds__(256) void k_splitA(
    const float* __restrict__ q, const float* __restrict__ k,
    const float* __restrict__ v, bh_t* __restrict__ dst)
{
    const int z = blockIdx.y;
    const float* in = (z == 0) ? q : (z == 1) ? k : v;
    size_t idx = ((size_t)blockIdx.x * 256 + threadIdx.x) * 8;
    float4 v0 = *(const float4*)(in + idx);
    float4 v1 = *(const float4*)(in + idx + 4);
    float xs[8] = {v0.x, v0.y, v0.z, v0.w, v1.x, v1.y, v1.z, v1.w};
    bh8 h, l;
#pragma unroll
    for (int i = 0; i < 8; i++) {
        bh_t hh = (bh_t)xs[i];
        h[i] = hh;
        l[i] = (bh_t)(xs[i] - (float)hh);
    }
    if (z < 2) {
        bh_t* hp = dst + (size_t)z * 2 * PE;
        *(bh8*)(hp + idx)      = h;
        *(bh8*)(hp + PE + idx) = l;
    } else {
        *(bh8*)(dst + 4 * PE + idx) = h;
    }
}

// ---------------------------------------------------------------------------
// GEMM body: C[128x128 tile] = A[4096][1024](bf16 planes) @ W^T + bias.
// 4 waves (2x2), 64x64/wave = 4x4 frags -> 48 MFMA : 16 ds_read (split).
// Staging: pure bh8 load + ds_write (A pre-split by k_splitA).
// OMODE 0: bf16 hi+lo planes; 1: bf16 plane; 2: f32 (+KL fold); 3: VT layout.
template<bool SPLIT, int OMODE>
__device__ __forceinline__ void gemm_body(
    const bh_t* __restrict__ ABH, const bh_t* __restrict__ ABL,
    const bh_t* __restrict__ WH, const bh_t* __restrict__ WL,
    const float* __restrict__ bias,
    bh_t* __restrict__ oh, bh_t* __restrict__ ol, float* __restrict__ of,
    int n0, int m0)
{
    __shared__ __align__(16) bh_t Ah[128][40];
    __shared__ __align__(16) bh_t Al[128][40];
    __shared__ __align__(16) bh_t Bh[128][40];
    __shared__ __align__(16) bh_t Bl[128][40];
    const int t = threadIdx.x;
    const int lane = t & 63, w = t >> 6;
    const int lr = lane & 15, kg = lane >> 4;
    const int wm = (w & 1) * 64, wn = (w >> 1) * 64;
    const int ar = t >> 2, ac = (t & 3) * 8;
    f32x4 acc[4][4] = {};

    for (int kt = 0; kt < 1024; kt += 32) {
        __syncthreads();
        {
            size_t a0 = (size_t)(m0 + ar) * 1024 + kt + ac;
            size_t a1 = (size_t)(m0 + ar + 64) * 1024 + kt + ac;
            *(bh8*)&Ah[ar][ac]      = *(const bh8*)(ABH + a0);
            *(bh8*)&Ah[ar + 64][ac] = *(const bh8*)(ABH + a1);
            if constexpr (SPLIT) {
                *(bh8*)&Al[ar][ac]      = *(const bh8*)(ABL + a0);
                *(bh8*)&Al[ar + 64][ac] = *(const bh8*)(ABL + a1);
            }
            size_t b0 = (size_t)(n0 + ar) * 1024 + kt + ac;
            size_t b1 = (size_t)(n0 + ar + 64) * 1024 + kt + ac;
            *(bh8*)&Bh[ar][ac]      = *(const bh8*)(WH + b0);
            *(bh8*)&Bh[ar + 64][ac] = *(const bh8*)(WH + b1);
            if constexpr (SPLIT) {
                *(bh8*)&Bl[ar][ac]      = *(const bh8*)(WL + b0);
                *(bh8*)&Bl[ar + 64][ac] = *(const bh8*)(WL + b1);
            }
        }
        __syncthreads();
        bh8 bfh[4], bfl[4];
#pragma unroll
        for (int fn = 0; fn < 4; fn++) {
            bfh[fn] = *(bh8*)&Bh[wn + fn*16 + lr][kg * 8];
            if constexpr (SPLIT) bfl[fn] = *(bh8*)&Bl[wn + fn*16 + lr][kg * 8];
        }
#pragma unroll
        for (int fm = 0; fm < 4; fm++) {
            bh8 a_h = *(bh8*)&Ah[wm + fm*16 + lr][kg * 8];
            bh8 a_l;
            if constexpr (SPLIT) a_l = *(bh8*)&Al[wm + fm*16 + lr][kg * 8];
#pragma unroll
            for (int fn = 0; fn < 4; fn++) {
                acc[fm][fn] = MFMA_BF16(a_h, bfh[fn], acc[fm][fn], 0, 0, 0);
                if constexpr (SPLIT) {
                    acc[fm][fn] = MFMA_BF16(a_h, bfl[fn], acc[fm][fn], 0, 0, 0);
                    acc[fm][fn] = MFMA_BF16(a_l, bfh[fn], acc[fm][fn], 0, 0, 0);
                }
            }
        }
    }
#pragma unroll
    for (int fm = 0; fm < 4; fm++)
#pragma unroll
    for (int fn = 0; fn < 4; fn++) {
        int col = n0 + wn + fn*16 + lr;
        float bv = bias[col];
#pragma unroll
        for (int r = 0; r < 4; r++) {
            int row = m0 + wm + fm*16 + kg*4 + r;
            float c = acc[fm][fn][r] + bv;
            size_t idx = (size_t)row * 1024 + col;
            if constexpr (OMODE == 0) {
                bh_t hh = (bh_t)c;
                oh[idx] = hh;
                ol[idx] = (bh_t)(c - (float)hh);
            } else if constexpr (OMODE == 1) {
                oh[idx] = (bh_t)c;
            } else if constexpr (OMODE == 2) {
                of[idx] = c;
            } else {
                // VT layout: [(b*16+h)*64+dv][l], h=col>>6, dv=col&63
                int bb = row >> 9, ll = row & 511;
                oh[(((size_t)(bb*16 + (col >> 6)) * 64) + (col & 63)) * 512 + ll] = (bh_t)c;
            }
        }
    }
}

// plain GEMM wrapper (V-projection OMODE 3, output GEMM OMODE 2 + KL fold)
template<int OMODE>
__global__ __launch_bounds__(256) void k_gemm(
    const bh_t* __restrict__ ABH,
    const bh_t* __restrict__ WH, const bh_t* __restrict__ WL,
    const float* __restrict__ bias,
    bh_t* __restrict__ oh, float* __restrict__ of,
    const double* __restrict__ acc)
{
    gemm_body<false, OMODE>(ABH, nullptr, WH, WL, bias, oh, nullptr, of,
                            blockIdx.x * 128, blockIdx.y * 128);
    if constexpr (OMODE == 2) {
        if (blockIdx.x == 0 && blockIdx.y == 0 && threadIdx.x == 0) {
            // S2 = sum(exp(log(softmax+1e-20))) = B*H*L exactly
            double kl = (-acc[0] + 512.0 * acc[2] + 65536.0) / 33554432.0;
            of[4194304] = (float)kl;
        }
    }
}

// fused Q+K split projections: z selects planes (A, W, bias, out contiguous)
__global__ __launch_bounds__(256) void k_gemm_qk(
    const bh_t* __restrict__ Abase, const bh_t* __restrict__ Wbase,
    const float* __restrict__ bq, const float* __restrict__ bk,
    bh_t* __restrict__ Obase)
{
    const int z = blockIdx.z;
    const bh_t* AH = Abase + (size_t)z * 2 * PE;
    const bh_t* WH = Wbase + (size_t)z * 2ull * 1024ull * 1024ull;
    bh_t* oh = Obase + (size_t)z * 2 * PE;
    gemm_body<true, 0>(AH, AH + PE, WH, WH + 1024ull*1024ull,
                       z ? bk : bq, oh, oh + PE, nullptr,
                       blockIdx.x * 128, blockIdx.y * 128);
}

// dot_gamma[b,h,l] = Wp2 . leakyrelu(K_head[b,h,l,:] @ Wp1 + bp1) + bp2
__global__ __launch_bounds__(256) void k_prior(
    const bh_t* __restrict__ KH, const bh_t* __restrict__ WP1T,
    const float* __restrict__ bp1, const float* __restrict__ wp2,
    const float* __restrict__ bp2, float* __restrict__ DG)
{
    __shared__ __align__(16) bh_t Kt[64][72];
    __shared__ __align__(16) bh_t Wt[64][72];
    const int lt = blockIdx.x, h = blockIdx.y, b = blockIdx.z;
    const int t = threadIdx.x, lane = t & 63, w = t >> 6;
    const int lr = lane & 15, kg = lane >> 4;
    {
        int r = t >> 2, j0 = (t & 3) * 16;
        const bh_t* src = KH + ((size_t)(b*512 + lt*64 + r)) * 1024 + h*64 + j0;
        *(bh8*)&Kt[r][j0]     = *(const bh8*)src;
        *(bh8*)&Kt[r][j0 + 8] = *(const bh8*)(src + 8);
    }
    __syncthreads();
    bh8 af0 = *(bh8*)&Kt[w*16 + lr][kg * 8];
    bh8 af1 = *(bh8*)&Kt[w*16 + lr][32 + kg * 8];
    float dgp[4] = {0.f, 0.f, 0.f, 0.f};
    for (int dt = 0; dt < 16; dt++) {
        __syncthreads();
        {
            int r = t >> 2, j0 = (t & 3) * 16;
            const bh_t* src = WP1T + (size_t)(dt*64 + r) * 64 + j0;
            *(bh8*)&Wt[r][j0]     = *(const bh8*)src;
            *(bh8*)&Wt[r][j0 + 8] = *(const bh8*)(src + 8);
        }
        __syncthreads();
#pragma unroll
        for (int fn = 0; fn < 4; fn++) {
            bh8 b0 = *(bh8*)&Wt[fn*16 + lr][kg * 8];
            bh8 b1 = *(bh8*)&Wt[fn*16 + lr][32 + kg * 8];
            f32x4 acc = {};
            acc = MFMA_BF16(af0, b0, acc, 0, 0, 0);
            acc = MFMA_BF16(af1, b1, acc, 0, 0, 0);
            int d = dt*64 + fn*16 + lr;
            float bpv = bp1[d], wvv = wp2[d];
#pragma unroll
            for (int r = 0; r < 4; r++) {
                float hv = acc[r] + bpv;
                hv = (hv >= 0.f) ? hv : 0.01f * hv;
                dgp[r] = fmaf(hv, wvv, dgp[r]);
            }
        }
    }
#pragma unroll
    for (int r = 0; r < 4; r++) {
        float v = dgp[r];
        v += __shfl_xor(v, 1); v += __shfl_xor(v, 2);
        v += __shfl_xor(v, 4); v += __shfl_xor(v, 8);
        dgp[r] = v;
    }
    if (lr == 0) {
        float b2 = bp2[0];
        int bh = b * 16 + h;
#pragma unroll
        for (int r = 0; r < 4; r++)
            DG[(size_t)bh*512 + lt*64 + w*16 + kg*4 + r] = dgp[r] + b2;
    }
}

// alpha = softmax_k(dot_gamma); accumulate alpha-only KL terms into acc[2]
__global__ __launch_bounds__(512) void k_alpha(
    const float* __restrict__ DG, float* __restrict__ AL, double* __restrict__ acc)
{
    __shared__ float red[512];
    const int bh = blockIdx.x, t = threadIdx.x;
    float v = DG[(size_t)bh * 512 + t];
    red[t] = v; __syncthreads();
    for (int s = 256; s > 0; s >>= 1) { if (t < s) red[t] = fmaxf(red[t], red[t+s]); __syncthreads(); }
    float m = red[0]; __syncthreads();
    float e = expf(v - m);
    red[t] = e; __syncthreads();
    for (int s = 256; s > 0; s >>= 1) { if (t < s) red[t] += red[t+s]; __syncthreads(); }
    float ssum = red[0]; __syncthreads();
    float a = e / ssum;                 // * BETA_GAMMA (=1)
    AL[(size_t)bh * 512 + t] = a;
    // lg1 + 2*eulergamma = 0.6931471805599453 + 1.1544313298030658
    float t2 = a * 1.8475785103630112f + lgammaf(a + 1e-20f);
    red[t] = t2; __syncthreads();
    for (int s = 256; s > 0; s >>= 1) { if (t < s) red[t] += red[t+s]; __syncthreads(); }
    if (t == 0) atomicAdd(&acc[2], (double)red[0]);
}

// fused stochastic attention: one block per (b,h, 128-row q-chunk), 8 waves.
// pass A: QK split-MFMA + online (M1,Z1) + G chain -> fp16 spill (interleaved)
// pass B: K-restage + 3-MFMA logit recompute + exp/log + softmax-2 + PV (Vt LDS)
__global__ __launch_bounds__(512, 3) void k_attn(
    const bh_t* __restrict__ QH, const bh_t* __restrict__ QL,
    const bh_t* __restrict__ KH, const bh_t* __restrict__ KL,
    const bh_t* __restrict__ VT, const float* __restrict__ U,
    const float* __restrict__ AL, bh_t* __restrict__ HOB,
    hf_t* __restrict__ GS, double* __restrict__ acc)
{
    __shared__ __align__(16) bh_t KtH[64][72];
    __shared__ __align__(16) bh_t KtL[64][72];
    __shared__ __align__(16) bh_t Vt[64][72];
    __shared__ __align__(16) bh_t Sl[8][16][72];
    __shared__ float Asm[64];
    __shared__ float red[512];

    const int flat = blockIdx.x;
    const int bh = flat & 127, qc = flat >> 7;   // 4 q-chunks of one bh share an XCD
    const int b = bh >> 4, h = bh & 15;
    const int t = threadIdx.x, w = t >> 6, lane = t & 63;
    const int lr = lane & 15, kg = lane >> 4;
    const int q0 = qc * 128 + w * 16;
    const int sr = t >> 3, sj = (t & 7) * 8;
    const float* Up = U + ((size_t)bh * 512 + q0 + kg * 4) * 512;
    hf_t* GSp = GS + (size_t)flat * 65536 + (size_t)w * 8192;

    bh8 qh[2], ql[2];
    {
        size_t qb = ((size_t)(b * 512) + q0 + lr) * 1024 + h * 64;
        qh[0] = *(const bh8*)(QH + qb + kg * 8);
        qh[1] = *(const bh8*)(QH + qb + 32 + kg * 8);
        ql[0] = *(const bh8*)(QL + qb + kg * 8);
        ql[1] = *(const bh8*)(QL + qb + 32 + kg * 8);
    }
    float C[4];   // per-q-row M1 + lnZ1, carried A -> B

    // ---- pass A: logits (split-bf16 MFMA), G chain + fp16 spill, M1/Z1 ----
    {
        float M1[4], Z1[4];
#pragma unroll
        for (int r = 0; r < 4; r++) { M1[r] = -INFINITY; Z1[r] = 0.f; }

        for (int kt = 0; kt < 8; kt++) {
            __syncthreads();
            {
                size_t src = ((size_t)(b*512 + kt*64 + sr)) * 1024 + h*64 + sj;
                *(bh8*)&KtH[sr][sj] = *(const bh8*)(KH + src);
                *(bh8*)&KtL[sr][sj] = *(const bh8*)(KL + src);
            }
            __syncthreads();
            f32x4 av[4];
#pragma unroll
            for (int fn = 0; fn < 4; fn++) {
                f32x4 a = {};
#pragma unroll
                for (int ks = 0; ks < 2; ks++) {
                    bh8 kb  = *(bh8*)&KtH[fn*16 + lr][ks*32 + kg*8];
                    bh8 kl2 = *(bh8*)&KtL[fn*16 + lr][ks*32 + kg*8];
                    a = MFMA_BF16(qh[ks], kb,  a, 0, 0, 0);
                    a = MFMA_BF16(qh[ks], kl2, a, 0, 0, 0);
                    a = MFMA_BF16(ql[ks], kb,  a, 0, 0, 0);
                }
#pragma unroll
                for (int r = 0; r < 4; r++) a[r] *= 8.0f;   // att / SCALE, SCALE=1/8
                av[fn] = a;
                // Gumbel/lgamma chain — independent of the MFMAs above, fills
                // their latency; spill G (fp16) in fragment layout.
                int k = kt * 64 + fn * 16 + lr;
                hf4 gh;
#pragma unroll
                for (int r = 0; r < 4; r++) {
                    float u  = Up[(size_t)r * 512 + k];
                    float tt = (1.0f - u) + 1e-20f;
                    float gl = 1e-20f - __logf(tt);
                    float g  = __logf(gl);
                    gh[r] = (hf_t)lgamma_fast(fmaf(2.0f, g, 3.0f)); // 1+1/k+(1/k)*gumbel
                }
                *(hf4*)(GSp + ((size_t)(kt*4 + fn) * 64 + lane) * 4) = gh;
            }
#pragma unroll
            for (int r = 0; r < 4; r++) {
                float mx = fmaxf(fmaxf(av[0][r], av[1][r]), fmaxf(av[2][r], av[3][r]));
                mx = fmaxf(mx, __shfl_xor(mx, 1));
                mx = fmaxf(mx, __shfl_xor(mx, 2));
                mx = fmaxf(mx, __shfl_xor(mx, 4));
                mx = fmaxf(mx, __shfl_xor(mx, 8));
                float nm = fmaxf(M1[r], mx);
                float es = __expf(av[0][r]-nm) + __expf(av[1][r]-nm)
                         + __expf(av[2][r]-nm) + __expf(av[3][r]-nm);
                es += __shfl_xor(es, 1); es += __shfl_xor(es, 2);
                es += __shfl_xor(es, 4); es += __shfl_xor(es, 8);
                Z1[r] = Z1[r] * __expf(M1[r] - nm) + es;
                M1[r] = nm;
            }
        }
#pragma unroll
        for (int r = 0; r < 4; r++) C[r] = M1[r] + logf(Z1[r]);
    }

    // ---- pass B: restage K+V; recompute s; lp + spilled G; softmax-2 + PV --
    float M2[4], Z2[4];
    f32x4 oacc[4] = {};
#pragma unroll
    for (int r = 0; r < 4; r++) { M2[r] = -INFINITY; Z2[r] = 0.f; }
    float S1f = 0.f;

    for (int kt = 0; kt < 8; kt++) {
        __syncthreads();
        {   // stage K hi/lo + V^T tile (all vectorized) + alpha tile
            size_t src = ((size_t)(b*512 + kt*64 + sr)) * 1024 + h*64 + sj;
            *(bh8*)&KtH[sr][sj] = *(const bh8*)(KH + src);
            *(bh8*)&KtL[sr][sj] = *(const bh8*)(KL + src);
            const bh_t* vsrc = VT + ((size_t)bh * 64 + sr) * 512 + kt*64 + sj;
            *(bh8*)&Vt[sr][sj] = *(const bh8*)vsrc;
            if (t < 64) Asm[t] = AL[(size_t)bh * 512 + kt * 64 + t];
        }
        __syncthreads();
        f32x4 wv[4];
#pragma unroll
        for (int fn = 0; fn < 4; fn++) {
            f32x4 a = {};
#pragma unroll
            for (int ks = 0; ks < 2; ks++) {
                bh8 kb  = *(bh8*)&KtH[fn*16 + lr][ks*32 + kg*8];
                bh8 kl2 = *(bh8*)&KtL[fn*16 + lr][ks*32 + kg*8];
                a = MFMA_BF16(qh[ks], kb,  a, 0, 0, 0);
                a = MFMA_BF16(qh[ks], kl2, a, 0, 0, 0);
                a = MFMA_BF16(ql[ks], kb,  a, 0, 0, 0);
            }
            hf4 gh = *(const hf4*)(GSp + ((size_t)(kt*4 + fn) * 64 + lane) * 4);
            float alv = Asm[fn * 16 + lr];
#pragma unroll
            for (int r = 0; r < 4; r++) {
                float s  = fmaf(a[r], 8.0f, -C[r]);      // logit - (M1+lnZ1)
                float ex = __expf(s);                     // = softmax-1 prob
                float lp = __logf(ex + 1e-20f);           // exact EPS-floor
                wv[fn][r] = lp - (float)gh[r];
                S1f = fmaf(alv, lp, S1f);
            }
        }
#pragma unroll
        for (int r = 0; r < 4; r++) {
            float mx = fmaxf(fmaxf(wv[0][r], wv[1][r]), fmaxf(wv[2][r], wv[3][r]));
            mx = fmaxf(mx, __shfl_xor(mx, 1));
            mx = fmaxf(mx, __shfl_xor(mx, 2));
            mx = fmaxf(mx, __shfl_xor(mx, 4));
            mx = fmaxf(mx, __shfl_xor(mx, 8));
            float nm = fmaxf(M2[r], mx);
            float sc = __expf(M2[r] - nm);               // exp(-inf)=0, exp(0)=1
            float zs = 0.f;
#pragma unroll
            for (int fn = 0; fn < 4; fn++) {
                float sv = __expf(wv[fn][r] - nm);
                zs += sv;
                Sl[w][kg * 4 + r][fn * 16 + lr] = (bh_t)sv;
            }
            zs += __shfl_xor(zs, 1); zs += __shfl_xor(zs, 2);
            zs += __shfl_xor(zs, 4); zs += __shfl_xor(zs, 8);
            Z2[r] = fmaf(Z2[r], sc, zs);
            M2[r] = nm;
#pragma unroll
            for (int fo = 0; fo < 4; fo++) oacc[fo][r] *= sc;
        }
        // no extra barrier: Sl slice is per-wave (program-ordered); Vt/KtH
        // staged behind barrier and only rewritten after next loop-top barrier.
        bh8 sa0 = *(bh8*)&Sl[w][lr][kg*8];
        bh8 sa1 = *(bh8*)&Sl[w][lr][32 + kg*8];
#pragma unroll
        for (int fo = 0; fo < 4; fo++) {
            bh8 v0 = *(bh8*)&Vt[fo*16 + lr][kg*8];
            bh8 v1 = *(bh8*)&Vt[fo*16 + lr][32 + kg*8];
            oacc[fo] = MFMA_BF16(sa0, v0, oacc[fo], 0, 0, 0);
            oacc[fo] = MFMA_BF16(sa1, v1, oacc[fo], 0, 0, 0);
        }
    }
    float rz[4];
#pragma unroll
    for (int r = 0; r < 4; r++) rz[r] = 1.0f / Z2[r];
    // head output (bf16): HO[b, q, h*64+dv]
#pragma unroll
    for (int fo = 0; fo < 4; fo++) {
#pragma unroll
        for (int r = 0; r < 4; r++) {
            int q = q0 + kg * 4 + r;
            int dv = fo * 16 + lr;
            HOB[((size_t)(b * 512 + q)) * 1024 + h * 64 + dv] = (bh_t)(oacc[fo][r] * rz[r]);
        }
    }
    red[t] = S1f; __syncthreads();
    for (int s = 256; s > 0; s >>= 1) { if (t < s) red[t] += red[t+s]; __syncthreads(); }
    if (t == 0) atomicAdd(&acc[0], (double)red[0]);
}

// ---------------------------------------------------------------------------
extern "C" void kernel_launch(void* const* d_in, const int* in_sizes, int n_in,
                              void* d_out, int out_size, void* d_ws, size_t ws_size,
                              hipStream_t stream)
{
    (void)in_sizes; (void)n_in; (void)d_ws; (void)ws_size; (void)out_size;
    const float* queries = (const float*)d_in[0];
    const float* keys    = (const float*)d_in[1];
    const float* values  = (const float*)d_in[2];
    const float* unif    = (const float*)d_in[3];
    const float* Wq = (const float*)d_in[4];  const float* bq = (const float*)d_in[5];
    const float* Wk = (const float*)d_in[6];  const float* bk = (const float*)d_in[7];
    const float* Wv = (const float*)d_in[8];  const float* bv = (const float*)d_in[9];
    const float* Wo = (const float*)d_in[10]; const float* bo = (const float*)d_in[11];
    const float* Wp1 = (const float*)d_in[12]; const float* bp1 = (const float*)d_in[13];
    const float* Wp2 = (const float*)d_in[14]; const float* bp2 = (const float*)d_in[15];

    unsigned char* ws = nullptr;
    hipGetSymbolAddress((void**)&ws, HIP_SYMBOL(g_ws));

    bh_t* QHI = (bh_t*)(ws + O_QHI); bh_t* QLO = (bh_t*)(ws + O_QLO);
    bh_t* KHI = (bh_t*)(ws + O_KHI); bh_t* KLO = (bh_t*)(ws + O_KLO);
    bh_t* VTp = (bh_t*)(ws + O_VT);
    bh_t* WQH = (bh_t*)(ws + O_WQH);
    bh_t* WVH = (bh_t*)(ws + O_WVH); bh_t* WVL = (bh_t*)(ws + O_WVL);
    bh_t* WOH = (bh_t*)(ws + O_WOH); bh_t* WOL = (bh_t*)(ws + O_WOL);
    bh_t* WP1H = (bh_t*)(ws + O_WP1H); bh_t* WP1L = (bh_t*)(ws + O_WP1L);
    float* DG    = (float*)(ws + O_DG);
    float* ALPHA = (float*)(ws + O_ALPHA);
    bh_t*  HOB   = (bh_t*)(ws + O_HO);
    hf_t*  GS    = (hf_t*)(ws + O_GS);
    double* ACC  = (double*)(ws + O_ACC);
    bh_t*  AQH   = (bh_t*)(ws + O_AQH);
    bh_t*  AVH   = AQH + 4 * PE;
    float* outF  = (float*)d_out;

    // weight transposes (+ ACC zeroing) and activation pre-split
    k_transpose_split4<<<dim3(16,16,4), 256, 0, stream>>>(Wq, Wk, Wv, Wo, WQH, ACC);
    k_transpose_split<<<dim3(16,1), 256, 0, stream>>>(Wp1, WP1H, WP1L, 64, 1024);
    k_splitA<<<dim3(2048,3), 256, 0, stream>>>(queries, keys, values, AQH);

    // Q and K split projections fused (z=2); V projection writes VT directly
    k_gemm_qk<<<dim3(8,32,2), 256, 0, stream>>>(AQH, WQH, bq, bk, QHI);
    k_gemm<3><<<dim3(8,32), 256, 0, stream>>>(AVH, WVH, WVL, bv, VTp, nullptr, nullptr);

    k_prior<<<dim3(8,16,8), 256, 0, stream>>>(KHI, WP1H, bp1, Wp2, bp2, DG);
    k_alpha<<<128, 512, 0, stream>>>(DG, ALPHA, ACC);

    k_attn<<<512, 512, 0, stream>>>(QHI, QLO, KHI, KLO, VTp, unif, ALPHA, HOB, GS, ACC);

    // output GEMM (f32) + KL finalization folded into its epilogue
    k_gemm<2><<<dim3(8,32), 256, 0, stream>>>(HOB, WOH, WOL, bo, nullptr, outF, ACC);
}